// Round 2
// baseline (718.033 us; speedup 1.0000x reference)
//
#include <hip/hip_runtime.h>
#include <hip/hip_bf16.h>

#define B 128
#define N 2048
#define E 16384
#define F 32
#define H 64
#define OUTD 16

__device__ __forceinline__ float b2f(unsigned short u) {
    return __uint_as_float(((unsigned int)u) << 16);
}
__device__ __forceinline__ unsigned short f2b(float f) {
    unsigned int x = __float_as_uint(f);
    unsigned int r = (x + 0x7FFFu + ((x >> 16) & 1u)) >> 16;  // RNE, finite inputs
    return (unsigned short)r;
}

struct ConvArgs {
    const void* src[9];
    float* dst[9];
};

// ---------------------------------------------------------------------------
// K0: dtype flags. Blocks 0..8: float arrays — flag=1 if bf16, 0 if f32.
// Probe: reinterpret first K elements as bf16; true-f32 data's low mantissa
// halves yield huge magnitudes (clipped to 1e6) -> mean >> 100.
// Block 9: mask encoding. mask[0]=mask[1]=true always (n >= 1024).
//   bf16 1.0 bytes: [0x80,0x3F]; byte bool: [1,1]; int32: [1,0,0,0,1,..];
//   int64: [1,0,0,0,0,..]; f32 1.0: [0,0,0x80,0x3F].
// ---------------------------------------------------------------------------
__global__ __launch_bounds__(256) void k_flags(ConvArgs ca, const void* mask,
                                               int* flags) {
    const int a = blockIdx.x;
    const int t = threadIdx.x;
    if (a == 9) {
        if (t == 0) {
            const unsigned char* mb = (const unsigned char*)mask;
            int mode;
            if (mb[0] == 0x80 && mb[1] == 0x3F) mode = 2;        // bf16
            else if (mb[0] != 0 && mb[1] != 0) mode = 0;         // bytes
            else if (mb[0] != 0) mode = (mb[4] != 0) ? 1 : 4;    // int32 : int64
            else mode = 3;                                       // f32 (4B nonzero)
            flags[9] = mode;
        }
        return;
    }
    int n;
    switch (a) {
        case 0: n = B * N * F; break;   // node_features
        case 1: n = F * H; break;       // W1
        case 2: n = H; break;           // b1
        case 3: n = H * H; break;       // W2
        case 4: n = H; break;           // b2
        case 5: n = H * H; break;       // aW1
        case 6: n = H; break;           // ab1
        case 7: n = H * OUTD; break;    // aW2
        default: n = OUTD; break;       // ab2
    }
    const int K = n < 1024 ? n : 1024;
    const unsigned short* p = (const unsigned short*)ca.src[a];
    float s = 0.f;
    for (int i = t; i < K; i += 256) s += fminf(fabsf(b2f(p[i])), 1e6f);
    __shared__ float red[256];
    red[t] = s;
    __syncthreads();
    for (int st = 128; st > 0; st >>= 1) {
        if (t < st) red[t] += red[t + st];
        __syncthreads();
    }
    if (t == 0) flags[a] = (red[0] < 100.0f * (float)K) ? 1 : 0;
}

// ---------------------------------------------------------------------------
// K1: convert all 9 float arrays to staged f32, branching on flags.
// Block->array map (cumulative blocks): x:32768, W1:8, b1:1, W2:16, b2:1,
// aW1:16, ab1:1, aW2:4, ab2:1 -> 32816 total.
// ---------------------------------------------------------------------------
__global__ __launch_bounds__(256) void k_convert(ConvArgs ca,
                                                 const int* __restrict__ flags) {
    const int bid = blockIdx.x;
    int a, base, sz;
    if      (bid < 32768) { a = 0; base = bid;         sz = B * N * F; }
    else if (bid < 32776) { a = 1; base = bid - 32768; sz = F * H; }
    else if (bid < 32777) { a = 2; base = bid - 32776; sz = H; }
    else if (bid < 32793) { a = 3; base = bid - 32777; sz = H * H; }
    else if (bid < 32794) { a = 4; base = bid - 32793; sz = H; }
    else if (bid < 32810) { a = 5; base = bid - 32794; sz = H * H; }
    else if (bid < 32811) { a = 6; base = bid - 32810; sz = H; }
    else if (bid < 32815) { a = 7; base = bid - 32811; sz = H * OUTD; }
    else                  { a = 8; base = bid - 32815; sz = OUTD; }
    const int idx = base * 256 + threadIdx.x;
    if (idx >= sz) return;
    float v = flags[a] ? b2f(((const unsigned short*)ca.src[a])[idx])
                       : ((const float*)ca.src[a])[idx];
    ca.dst[a][idx] = v;
}

// ---------------------------------------------------------------------------
// K2: n[b] = count of nonzero mask elements, per detected encoding.
// ---------------------------------------------------------------------------
__global__ __launch_bounds__(256) void k_compute_n(const void* mask,
                                                   const int* __restrict__ flags,
                                                   int* __restrict__ n_arr) {
    const int b = blockIdx.x;
    const int t = threadIdx.x;
    const int mode = flags[9];
    int cnt = 0;
    if (mode == 0) {
        const unsigned char* r = (const unsigned char*)mask + (size_t)b * N;
        for (int i = t; i < N; i += 256) cnt += (r[i] != 0);
    } else if (mode == 1 || mode == 3) {
        const unsigned int* r = (const unsigned int*)mask + (size_t)b * N;
        for (int i = t; i < N; i += 256) cnt += (r[i] != 0);
    } else if (mode == 2) {
        const unsigned short* r = (const unsigned short*)mask + (size_t)b * N;
        for (int i = t; i < N; i += 256) cnt += (r[i] != 0);
    } else {
        const unsigned long long* r = (const unsigned long long*)mask + (size_t)b * N;
        for (int i = t; i < N; i += 256) cnt += (r[i] != 0ULL);
    }
    __shared__ int sdata[256];
    sdata[t] = cnt;
    __syncthreads();
    for (int s = 128; s > 0; s >>= 1) {
        if (t < s) sdata[t] += sdata[t + s];
        __syncthreads();
    }
    if (t == 0) {
        int n = sdata[0];
        n_arr[b] = (n > N) ? N : n;
    }
}

// ---------------------------------------------------------------------------
// K3: zero the degree counters (kernel-based; no hipMemsetAsync dependence)
// ---------------------------------------------------------------------------
__global__ __launch_bounds__(256) void k_zero(int* __restrict__ p) {
    p[blockIdx.x * 256 + threadIdx.x] = 0;
}

// ---------------------------------------------------------------------------
// K4: count[b*N + dst] += 1 for each valid edge (src<n && dst<n)
// ---------------------------------------------------------------------------
__global__ __launch_bounds__(256) void k_count(const int* __restrict__ eidx,
                                               const int* __restrict__ n_arr,
                                               int* __restrict__ count) {
    const int i = blockIdx.x * 256 + threadIdx.x;
    const int b = i >> 14;  // / E
    const int e = i & (E - 1);
    const int n = n_arr[b];
    const int src = eidx[(size_t)b * 2 * E + e];
    const int dst = eidx[(size_t)b * 2 * E + E + e];
    if ((unsigned)src < (unsigned)n && (unsigned)dst < (unsigned)n)
        atomicAdd(&count[b * N + dst], 1);
}

// ---------------------------------------------------------------------------
// K5: per-batch exclusive scan of count -> offsets + cursor; fused
// dis[b,v] = (v < n) ? rsqrt(count+1) : 0
// ---------------------------------------------------------------------------
__global__ __launch_bounds__(256) void k_scan(const int* __restrict__ count,
                                              const int* __restrict__ n_arr,
                                              int* __restrict__ offsets,
                                              int* __restrict__ cursor,
                                              float* __restrict__ dis) {
    const int b = blockIdx.x;
    const int t = threadIdx.x;
    const int n = n_arr[b];
    const int base = b * N + t * 8;
    int c[8];
    int s = 0;
#pragma unroll
    for (int j = 0; j < 8; j++) {
        int v = count[base + j];
        c[j] = (v < 0) ? 0 : v;
        s += c[j];
    }
    __shared__ int part[256];
    part[t] = s;
    __syncthreads();
    for (int offd = 1; offd < 256; offd <<= 1) {
        int v = (t >= offd) ? part[t - offd] : 0;
        __syncthreads();
        part[t] += v;
        __syncthreads();
    }
    int run = part[t] - s;
#pragma unroll
    for (int j = 0; j < 8; j++) {
        offsets[base + j] = run;
        cursor[base + j] = run;
        dis[base + j] = ((t * 8 + j) < n) ? rsqrtf((float)(c[j] + 1)) : 0.0f;
        run += c[j];
    }
}

// ---------------------------------------------------------------------------
// K6: CSR fill. sorted_src[b*E + pos] = src.
// ---------------------------------------------------------------------------
__global__ __launch_bounds__(256) void k_fill(const int* __restrict__ eidx,
                                              const int* __restrict__ n_arr,
                                              int* __restrict__ cursor,
                                              int* __restrict__ sorted_src) {
    const int i = blockIdx.x * 256 + threadIdx.x;
    const int b = i >> 14;
    const int e = i & (E - 1);
    const int n = n_arr[b];
    const int src = eidx[(size_t)b * 2 * E + e];
    const int dst = eidx[(size_t)b * 2 * E + E + e];
    if ((unsigned)src < (unsigned)n && (unsigned)dst < (unsigned)n) {
        int pos = atomicAdd(&cursor[b * N + dst], 1);
        if ((unsigned)pos < (unsigned)E) sorted_src[(size_t)b * E + pos] = src;
    }
}

// ---------------------------------------------------------------------------
// K7: GEMM hW = in @ W. in (B*N, FIN) f32 or bf16; W (FIN,H) staged f32;
// out bf16. 16 rows/block, thread computes 4 cols.
// ---------------------------------------------------------------------------
template <bool BF16IN, int FIN>
__global__ __launch_bounds__(256) void k_gemm(const void* __restrict__ in,
                                              const float* __restrict__ W,
                                              unsigned short* __restrict__ out) {
    __shared__ float Ws[FIN * H];
    __shared__ float ins[16][FIN];
    const int tid = threadIdx.x;
    for (int i = tid; i < FIN * H; i += 256) Ws[i] = W[i];
    const size_t row0 = (size_t)blockIdx.x * 16;
    for (int i = tid; i < 16 * FIN; i += 256) {
        int r = i / FIN, f = i % FIN;
        size_t gi = (row0 + r) * FIN + f;
        ins[r][f] = BF16IN ? b2f(((const unsigned short*)in)[gi])
                           : ((const float*)in)[gi];
    }
    __syncthreads();
    const int r = tid >> 4;
    const int cg = (tid & 15) * 4;
    float a0 = 0.f, a1 = 0.f, a2 = 0.f, a3 = 0.f;
#pragma unroll
    for (int f = 0; f < FIN; f++) {
        float a = ins[r][f];
        float4 w = *(const float4*)&Ws[f * H + cg];
        a0 += a * w.x; a1 += a * w.y; a2 += a * w.z; a3 += a * w.w;
    }
    ushort4 o;
    o.x = f2b(a0); o.y = f2b(a1); o.z = f2b(a2); o.w = f2b(a3);
    *(ushort4*)&out[(row0 + r) * H + cg] = o;
}

// ---------------------------------------------------------------------------
// K8: aggregation. One wave per node, lane = feature.
// out[v,f] = relu(dv*(dv*hW[v,f] + sum_e dis[s]*hW[s,f]) + bias[f]), 0 invalid.
// ---------------------------------------------------------------------------
__global__ __launch_bounds__(256) void k_aggregate(
    const unsigned short* __restrict__ hW, const float* __restrict__ dis,
    const int* __restrict__ offsets, const int* __restrict__ count,
    const int* __restrict__ sorted_src, const float* __restrict__ bias,
    unsigned short* __restrict__ outb) {
    const int vg = (blockIdx.x * 256 + threadIdx.x) >> 6;
    const int lane = threadIdx.x & 63;
    const int bN = vg & ~(N - 1);
    const float dv = dis[vg];
    float res = 0.0f;
    if (dv > 0.0f) {
        float acc = dv * b2f(hW[(size_t)vg * H + lane]);
        int start = offsets[vg];
        if (start < 0) start = 0;
        if (start > E) start = E;
        int cnt = count[vg];
        if (cnt < 0) cnt = 0;
        if (cnt > E - start) cnt = E - start;
        const int* ss = sorted_src + (size_t)(vg >> 11) * E + start;
        for (int i = 0; i < cnt; i++) {
            int s = ss[i];
            acc += dis[bN + s] * b2f(hW[(size_t)(bN + s) * H + lane]);
        }
        res = fmaxf(dv * acc + bias[lane], 0.0f);
    }
    outb[(size_t)vg * H + lane] = f2b(res);
}

// ---------------------------------------------------------------------------
// K9: masked mean pool + 2-layer MLP head; out dtype follows input mode.
// ---------------------------------------------------------------------------
__global__ __launch_bounds__(256) void k_pool_mlp(
    const unsigned short* __restrict__ h2, const int* __restrict__ n_arr,
    const float* __restrict__ aW1, const float* __restrict__ ab1,
    const float* __restrict__ aW2, const float* __restrict__ ab2,
    const int* __restrict__ flags, void* __restrict__ out) {
    const int b = blockIdx.x;
    const int t = threadIdx.x;
    const int f = t & 63;
    const int chunk = t >> 6;  // 0..3
    const unsigned short* hb = h2 + (size_t)b * N * H;
    float s = 0.0f;
    for (int v = chunk; v < N; v += 4) s += b2f(hb[v * H + f]);
    __shared__ float red[4][64];
    __shared__ float pooled[64];
    __shared__ float hidden[64];
    red[chunk][f] = s;
    __syncthreads();
    if (t < 64) {
        int n = n_arr[b];
        if (n < 1) n = 1;
        pooled[t] = (red[0][t] + red[1][t] + red[2][t] + red[3][t]) / (float)n;
    }
    __syncthreads();
    if (t < 64) {
        float acc = ab1[t];
        for (int j = 0; j < 64; j++) acc += pooled[j] * aW1[j * 64 + t];
        hidden[t] = fmaxf(acc, 0.0f);
    }
    __syncthreads();
    if (t < 16) {
        float acc = ab2[t];
        for (int j = 0; j < 64; j++) acc += hidden[j] * aW2[j * 16 + t];
        if (flags[0]) ((unsigned short*)out)[b * OUTD + t] = f2b(acc);
        else          ((float*)out)[b * OUTD + t] = acc;
    }
}

// ---------------------------------------------------------------------------
extern "C" void kernel_launch(void* const* d_in, const int* in_sizes, int n_in,
                              void* d_out, int out_size, void* d_ws, size_t ws_size,
                              hipStream_t stream) {
    const void* x    = d_in[0];
    const int*  eidx = (const int*)d_in[1];
    const void* mask = d_in[2];

    char* ws = (char*)d_ws;
    size_t off = 0;
    auto alloc = [&](size_t bytes) -> void* {
        void* p = ws + off;
        off += (bytes + 255) & ~(size_t)255;
        return p;
    };
    int*   flags   = (int*)alloc(16 * sizeof(int));
    float* xf      = (float*)alloc((size_t)B * N * F * sizeof(float));
    float* W1f     = (float*)alloc(F * H * sizeof(float));
    float* b1f     = (float*)alloc(H * sizeof(float));
    float* W2f     = (float*)alloc(H * H * sizeof(float));
    float* b2f_    = (float*)alloc(H * sizeof(float));
    float* aW1f    = (float*)alloc(H * H * sizeof(float));
    float* ab1f    = (float*)alloc(H * sizeof(float));
    float* aW2f    = (float*)alloc(H * OUTD * sizeof(float));
    float* ab2f    = (float*)alloc(OUTD * sizeof(float));
    int*   n_arr   = (int*)alloc(B * sizeof(int));
    float* dis     = (float*)alloc((size_t)B * N * sizeof(float));
    int*   count   = (int*)alloc((size_t)B * N * sizeof(int));
    int*   offsets = (int*)alloc((size_t)B * N * sizeof(int));
    int*   cursor  = (int*)alloc((size_t)B * N * sizeof(int));
    int*   ssrc    = (int*)alloc((size_t)B * E * sizeof(int));
    unsigned short* bufA = (unsigned short*)alloc((size_t)B * N * H * 2);  // hW (bf16)
    unsigned short* bufB = (unsigned short*)alloc((size_t)B * N * H * 2);  // h1/h2 (bf16)

    ConvArgs ca;
    ca.src[0] = x;        ca.dst[0] = xf;
    ca.src[1] = d_in[3];  ca.dst[1] = W1f;
    ca.src[2] = d_in[4];  ca.dst[2] = b1f;
    ca.src[3] = d_in[5];  ca.dst[3] = W2f;
    ca.src[4] = d_in[6];  ca.dst[4] = b2f_;
    ca.src[5] = d_in[7];  ca.dst[5] = aW1f;
    ca.src[6] = d_in[8];  ca.dst[6] = ab1f;
    ca.src[7] = d_in[9];  ca.dst[7] = aW2f;
    ca.src[8] = d_in[10]; ca.dst[8] = ab2f;

    k_flags<<<10, 256, 0, stream>>>(ca, mask, flags);
    k_convert<<<32816, 256, 0, stream>>>(ca, flags);
    k_compute_n<<<B, 256, 0, stream>>>(mask, flags, n_arr);
    k_zero<<<(B * N) / 256, 256, 0, stream>>>(count);
    k_count<<<(B * E) / 256, 256, 0, stream>>>(eidx, n_arr, count);
    k_scan<<<B, 256, 0, stream>>>(count, n_arr, offsets, cursor, dis);
    k_fill<<<(B * E) / 256, 256, 0, stream>>>(eidx, n_arr, cursor, ssrc);

    // Layer 1
    k_gemm<false, F><<<(B * N) / 16, 256, 0, stream>>>(xf, W1f, bufA);
    k_aggregate<<<(B * N) / 4, 256, 0, stream>>>(bufA, dis, offsets, count, ssrc, b1f, bufB);
    // Layer 2
    k_gemm<true, H><<<(B * N) / 16, 256, 0, stream>>>(bufB, W2f, bufA);
    k_aggregate<<<(B * N) / 4, 256, 0, stream>>>(bufA, dis, offsets, count, ssrc, b2f_, bufB);
    // Pool + MLP head
    k_pool_mlp<<<B, 256, 0, stream>>>(bufB, n_arr, aW1f, ab1f, aW2f, ab2f, flags, d_out);
}

// Round 3
// 476.857 us; speedup vs baseline: 1.5058x; 1.5058x over previous
//
#include <hip/hip_runtime.h>
#include <hip/hip_bf16.h>

#define B 128
#define N 2048
#define E 16384
#define F 32
#define H 64
#define OUTD 16

__device__ __forceinline__ float b2f(unsigned short u) {
    return __uint_as_float(((unsigned int)u) << 16);
}
__device__ __forceinline__ unsigned short f2b(float f) {
    unsigned int x = __float_as_uint(f);
    unsigned int r = (x + 0x7FFFu + ((x >> 16) & 1u)) >> 16;  // RNE, finite
    return (unsigned short)r;
}

struct ConvArgs {
    const void* src[9];
    float* dst[9];
};

// ---------------------------------------------------------------------------
// K0: dtype flags. Blocks 0..8: float arrays — flag=1 if bf16, 0 if f32.
// Block 9: mask encoding (mask[0]=mask[1]=true always since n>=1024), and
// writes flags[10]=1 (constant "bf16" flag used by GEMM2).
// ---------------------------------------------------------------------------
__global__ __launch_bounds__(256) void k_flags(ConvArgs ca, const void* mask,
                                               int* flags) {
    const int a = blockIdx.x;
    const int t = threadIdx.x;
    if (a == 9) {
        if (t == 0) {
            const unsigned char* mb = (const unsigned char*)mask;
            int mode;
            if (mb[0] == 0x80 && mb[1] == 0x3F) mode = 2;        // bf16
            else if (mb[0] != 0 && mb[1] != 0) mode = 0;         // bytes
            else if (mb[0] != 0) mode = (mb[4] != 0) ? 1 : 4;    // int32 : int64
            else mode = 3;                                       // f32
            flags[9] = mode;
            flags[10] = 1;  // constant: "input is bf16" for GEMM2
        }
        return;
    }
    int n;
    switch (a) {
        case 0: n = B * N * F; break;
        case 1: n = F * H; break;
        case 2: n = H; break;
        case 3: n = H * H; break;
        case 4: n = H; break;
        case 5: n = H * H; break;
        case 6: n = H; break;
        case 7: n = H * OUTD; break;
        default: n = OUTD; break;
    }
    const int K = n < 1024 ? n : 1024;
    const unsigned short* p = (const unsigned short*)ca.src[a];
    float s = 0.f;
    for (int i = t; i < K; i += 256) s += fminf(fabsf(b2f(p[i])), 1e6f);
    __shared__ float red[256];
    red[t] = s;
    __syncthreads();
    for (int st = 128; st > 0; st >>= 1) {
        if (t < st) red[t] += red[t + st];
        __syncthreads();
    }
    if (t == 0) flags[a] = (red[0] < 100.0f * (float)K) ? 1 : 0;
}

// ---------------------------------------------------------------------------
// K1: convert the 8 SMALL weight arrays (indices 1..8) to f32. x (index 0)
// is consumed directly by GEMM1 — no 100 MB staging copy.
// ---------------------------------------------------------------------------
__global__ __launch_bounds__(256) void k_convert_small(ConvArgs ca,
                                                       const int* __restrict__ flags) {
    const int a = blockIdx.x + 1;  // arrays 1..8
    int sz;
    switch (a) {
        case 1: sz = F * H; break;
        case 2: sz = H; break;
        case 3: sz = H * H; break;
        case 4: sz = H; break;
        case 5: sz = H * H; break;
        case 6: sz = H; break;
        case 7: sz = H * OUTD; break;
        default: sz = OUTD; break;
    }
    const int fl = flags[a];
    for (int i = threadIdx.x; i < sz; i += 256)
        ca.dst[a][i] = fl ? b2f(((const unsigned short*)ca.src[a])[i])
                          : ((const float*)ca.src[a])[i];
}

// ---------------------------------------------------------------------------
// K2: n[b] = count of nonzero mask elements, per detected encoding.
// ---------------------------------------------------------------------------
__global__ __launch_bounds__(256) void k_compute_n(const void* mask,
                                                   const int* __restrict__ flags,
                                                   int* __restrict__ n_arr) {
    const int b = blockIdx.x;
    const int t = threadIdx.x;
    const int mode = flags[9];
    int cnt = 0;
    if (mode == 0) {
        const unsigned char* r = (const unsigned char*)mask + (size_t)b * N;
        for (int i = t; i < N; i += 256) cnt += (r[i] != 0);
    } else if (mode == 1 || mode == 3) {
        const unsigned int* r = (const unsigned int*)mask + (size_t)b * N;
        for (int i = t; i < N; i += 256) cnt += (r[i] != 0);
    } else if (mode == 2) {
        const unsigned short* r = (const unsigned short*)mask + (size_t)b * N;
        for (int i = t; i < N; i += 256) cnt += (r[i] != 0);
    } else {
        const unsigned long long* r = (const unsigned long long*)mask + (size_t)b * N;
        for (int i = t; i < N; i += 256) cnt += (r[i] != 0ULL);
    }
    __shared__ int sdata[256];
    sdata[t] = cnt;
    __syncthreads();
    for (int s = 128; s > 0; s >>= 1) {
        if (t < s) sdata[t] += sdata[t + s];
        __syncthreads();
    }
    if (t == 0) {
        int n = sdata[0];
        n_arr[b] = (n > N) ? N : n;
    }
}

// ---------------------------------------------------------------------------
// K3: zero count (B*N ints) and pooled (B*H floats) in one kernel.
// ---------------------------------------------------------------------------
__global__ __launch_bounds__(256) void k_zero2(int* __restrict__ count,
                                               float* __restrict__ pooled) {
    const int i = blockIdx.x * 256 + threadIdx.x;
    if (i < B * N) count[i] = 0;
    const int j = i - B * N;
    if (j >= 0 && j < B * H) pooled[j] = 0.0f;
}

// ---------------------------------------------------------------------------
// K4: count[b*N + dst] += 1 for each valid edge
// ---------------------------------------------------------------------------
__global__ __launch_bounds__(256) void k_count(const int* __restrict__ eidx,
                                               const int* __restrict__ n_arr,
                                               int* __restrict__ count) {
    const int i = blockIdx.x * 256 + threadIdx.x;
    const int b = i >> 14;
    const int e = i & (E - 1);
    const int n = n_arr[b];
    const int src = eidx[(size_t)b * 2 * E + e];
    const int dst = eidx[(size_t)b * 2 * E + E + e];
    if ((unsigned)src < (unsigned)n && (unsigned)dst < (unsigned)n)
        atomicAdd(&count[b * N + dst], 1);
}

// ---------------------------------------------------------------------------
// K5: per-batch exclusive scan -> offsets + cursor; dis = rsqrt(deg+1) gate
// ---------------------------------------------------------------------------
__global__ __launch_bounds__(256) void k_scan(const int* __restrict__ count,
                                              const int* __restrict__ n_arr,
                                              int* __restrict__ offsets,
                                              int* __restrict__ cursor,
                                              float* __restrict__ dis) {
    const int b = blockIdx.x;
    const int t = threadIdx.x;
    const int n = n_arr[b];
    const int base = b * N + t * 8;
    int c[8];
    int s = 0;
#pragma unroll
    for (int j = 0; j < 8; j++) {
        int v = count[base + j];
        c[j] = (v < 0) ? 0 : v;
        s += c[j];
    }
    __shared__ int part[256];
    part[t] = s;
    __syncthreads();
    for (int offd = 1; offd < 256; offd <<= 1) {
        int v = (t >= offd) ? part[t - offd] : 0;
        __syncthreads();
        part[t] += v;
        __syncthreads();
    }
    int run = part[t] - s;
#pragma unroll
    for (int j = 0; j < 8; j++) {
        offsets[base + j] = run;
        cursor[base + j] = run;
        dis[base + j] = ((t * 8 + j) < n) ? rsqrtf((float)(c[j] + 1)) : 0.0f;
        run += c[j];
    }
}

// ---------------------------------------------------------------------------
// K6: CSR fill
// ---------------------------------------------------------------------------
__global__ __launch_bounds__(256) void k_fill(const int* __restrict__ eidx,
                                              const int* __restrict__ n_arr,
                                              int* __restrict__ cursor,
                                              int* __restrict__ sorted_src) {
    const int i = blockIdx.x * 256 + threadIdx.x;
    const int b = i >> 14;
    const int e = i & (E - 1);
    const int n = n_arr[b];
    const int src = eidx[(size_t)b * 2 * E + e];
    const int dst = eidx[(size_t)b * 2 * E + E + e];
    if ((unsigned)src < (unsigned)n && (unsigned)dst < (unsigned)n) {
        int pos = atomicAdd(&cursor[b * N + dst], 1);
        if ((unsigned)pos < (unsigned)E) sorted_src[(size_t)b * E + pos] = src;
    }
}

// ---------------------------------------------------------------------------
// K7: GEMM out = in @ W. 64 rows/block, thread computes 4 rows x 4 cols.
// in: bf16 or f32 per *bf16flag (device-side, wave-uniform). out bf16.
// ---------------------------------------------------------------------------
template <int FIN>
__global__ __launch_bounds__(256) void k_gemm(const void* __restrict__ in,
                                              const int* __restrict__ bf16flag,
                                              const float* __restrict__ W,
                                              unsigned short* __restrict__ out) {
    __shared__ float As[64][FIN + 4];  // +4 pad: breaks 4-way bank conflict
    __shared__ float Ws[FIN * H];
    const int tid = threadIdx.x;
    for (int i = tid; i < FIN * H; i += 256) Ws[i] = W[i];
    const size_t row0 = (size_t)blockIdx.x * 64;
    const int total = 64 * FIN;
    if (*bf16flag) {
        const unsigned short* ip = (const unsigned short*)in + row0 * FIN;
        for (int i = tid * 4; i < total; i += 1024) {
            ushort4 u = *(const ushort4*)(ip + i);
            int r = i / FIN, f = i & (FIN - 1);
            As[r][f] = b2f(u.x); As[r][f + 1] = b2f(u.y);
            As[r][f + 2] = b2f(u.z); As[r][f + 3] = b2f(u.w);
        }
    } else {
        const float* ip = (const float*)in + row0 * FIN;
        for (int i = tid * 4; i < total; i += 1024) {
            float4 u = *(const float4*)(ip + i);
            int r = i / FIN, f = i & (FIN - 1);
            As[r][f] = u.x; As[r][f + 1] = u.y;
            As[r][f + 2] = u.z; As[r][f + 3] = u.w;
        }
    }
    __syncthreads();
    const int r0 = (tid >> 4) * 4;
    const int cg = (tid & 15) * 4;
    float acc[4][4] = {};
    for (int f = 0; f < FIN; f++) {
        float4 w = *(const float4*)&Ws[f * H + cg];
#pragma unroll
        for (int rr = 0; rr < 4; rr++) {
            float a = As[r0 + rr][f];
            acc[rr][0] += a * w.x; acc[rr][1] += a * w.y;
            acc[rr][2] += a * w.z; acc[rr][3] += a * w.w;
        }
    }
#pragma unroll
    for (int rr = 0; rr < 4; rr++) {
        ushort4 o;
        o.x = f2b(acc[rr][0]); o.y = f2b(acc[rr][1]);
        o.z = f2b(acc[rr][2]); o.w = f2b(acc[rr][3]);
        *(ushort4*)&out[(row0 + r0 + rr) * H + cg] = o;
    }
}

// ---------------------------------------------------------------------------
// K8: aggregation, latency-optimized. One wave per node, lane = feature.
// Lane-parallel prefetch of edge srcs + dis, then __shfl broadcast and
// 4-wide batched independent hW row loads (MLP=4 instead of serial chase).
// ---------------------------------------------------------------------------
__global__ __launch_bounds__(256) void k_aggregate(
    const unsigned short* __restrict__ hW, const float* __restrict__ dis,
    const int* __restrict__ offsets, const int* __restrict__ count,
    const int* __restrict__ sorted_src, const float* __restrict__ bias,
    unsigned short* __restrict__ outb) {
    const int vg = (blockIdx.x * 256 + threadIdx.x) >> 6;
    const int lane = threadIdx.x & 63;
    const int bN = vg & ~(N - 1);
    const float dv = dis[vg];
    int start = offsets[vg];
    if (start < 0) start = 0;
    if (start > E) start = E;
    int cnt = count[vg];
    if (cnt < 0) cnt = 0;
    if (cnt > E - start) cnt = E - start;
    const int* ss = sorted_src + (size_t)(vg >> 11) * E + start;
    // lane-parallel prefetch (covers cnt <= 64; rare tail handled below)
    int pidx = (lane < cnt) ? ss[lane] : 0;
    float pdis = (lane < cnt) ? dis[bN + pidx] : 0.0f;
    float res = 0.0f;
    if (dv > 0.0f) {
        float acc = dv * b2f(hW[(size_t)vg * H + lane]);
        const int c64 = cnt < 64 ? cnt : 64;
        int i = 0;
        for (; i + 4 <= c64; i += 4) {
            int s0 = __shfl(pidx, i);     int s1 = __shfl(pidx, i + 1);
            int s2 = __shfl(pidx, i + 2); int s3 = __shfl(pidx, i + 3);
            float d0 = __shfl(pdis, i);     float d1 = __shfl(pdis, i + 1);
            float d2 = __shfl(pdis, i + 2); float d3 = __shfl(pdis, i + 3);
            float h0 = b2f(hW[(size_t)(bN + s0) * H + lane]);
            float h1 = b2f(hW[(size_t)(bN + s1) * H + lane]);
            float h2 = b2f(hW[(size_t)(bN + s2) * H + lane]);
            float h3 = b2f(hW[(size_t)(bN + s3) * H + lane]);
            acc = fmaf(d0, h0, acc); acc = fmaf(d1, h1, acc);
            acc = fmaf(d2, h2, acc); acc = fmaf(d3, h3, acc);
        }
        for (; i < c64; i++) {
            int s = __shfl(pidx, i);
            float d = __shfl(pdis, i);
            acc = fmaf(d, b2f(hW[(size_t)(bN + s) * H + lane]), acc);
        }
        for (; i < cnt; i++) {  // degree > 64: astronomically rare, correct anyway
            int s = ss[i];
            acc = fmaf(dis[bN + s], b2f(hW[(size_t)(bN + s) * H + lane]), acc);
        }
        res = fmaxf(fmaf(dv, acc, bias[lane]), 0.0f);
    }
    outb[(size_t)vg * H + lane] = f2b(res);
}

// ---------------------------------------------------------------------------
// K9: parallel pool partials. Grid = B*4; block sums 512 nodes -> atomicAdd.
// ---------------------------------------------------------------------------
__global__ __launch_bounds__(256) void k_pool_partial(
    const unsigned short* __restrict__ h2, float* __restrict__ pooled) {
    const int b = blockIdx.x >> 2;
    const int chunk = blockIdx.x & 3;
    const int f = threadIdx.x & 63;
    const int w = threadIdx.x >> 6;
    const unsigned short* hb = h2 + ((size_t)b * N + chunk * 512) * H;
    float s = 0.0f;
    for (int v = w; v < 512; v += 4) s += b2f(hb[(size_t)v * H + f]);
    __shared__ float red[4][64];
    red[w][f] = s;
    __syncthreads();
    if (w == 0)
        atomicAdd(&pooled[b * H + f],
                  red[0][f] + red[1][f] + red[2][f] + red[3][f]);
}

// ---------------------------------------------------------------------------
// K10: MLP head, one wave per batch.
// ---------------------------------------------------------------------------
__global__ __launch_bounds__(64) void k_mlp(
    const float* __restrict__ pooled, const int* __restrict__ n_arr,
    const float* __restrict__ aW1, const float* __restrict__ ab1,
    const float* __restrict__ aW2, const float* __restrict__ ab2,
    const int* __restrict__ flags, void* __restrict__ out) {
    const int b = blockIdx.x;
    const int t = threadIdx.x;
    __shared__ float p[64];
    __shared__ float hid[64];
    int n = n_arr[b];
    if (n < 1) n = 1;
    p[t] = pooled[b * H + t] / (float)n;
    __syncthreads();
    float acc = ab1[t];
    for (int j = 0; j < 64; j++) acc += p[j] * aW1[j * 64 + t];
    hid[t] = fmaxf(acc, 0.0f);
    __syncthreads();
    if (t < 16) {
        float a2 = ab2[t];
        for (int j = 0; j < 64; j++) a2 += hid[j] * aW2[j * 16 + t];
        if (flags[0]) ((unsigned short*)out)[b * OUTD + t] = f2b(a2);
        else          ((float*)out)[b * OUTD + t] = a2;
    }
}

// ---------------------------------------------------------------------------
extern "C" void kernel_launch(void* const* d_in, const int* in_sizes, int n_in,
                              void* d_out, int out_size, void* d_ws, size_t ws_size,
                              hipStream_t stream) {
    const void* x    = d_in[0];
    const int*  eidx = (const int*)d_in[1];
    const void* mask = d_in[2];

    char* ws = (char*)d_ws;
    size_t off = 0;
    auto alloc = [&](size_t bytes) -> void* {
        void* p = ws + off;
        off += (bytes + 255) & ~(size_t)255;
        return p;
    };
    int*   flags   = (int*)alloc(16 * sizeof(int));
    float* W1f     = (float*)alloc(F * H * sizeof(float));
    float* b1f     = (float*)alloc(H * sizeof(float));
    float* W2f     = (float*)alloc(H * H * sizeof(float));
    float* b2f_    = (float*)alloc(H * sizeof(float));
    float* aW1f    = (float*)alloc(H * H * sizeof(float));
    float* ab1f    = (float*)alloc(H * sizeof(float));
    float* aW2f    = (float*)alloc(H * OUTD * sizeof(float));
    float* ab2f    = (float*)alloc(OUTD * sizeof(float));
    int*   n_arr   = (int*)alloc(B * sizeof(int));
    float* dis     = (float*)alloc((size_t)B * N * sizeof(float));
    int*   count   = (int*)alloc((size_t)B * N * sizeof(int));
    int*   offsets = (int*)alloc((size_t)B * N * sizeof(int));
    int*   cursor  = (int*)alloc((size_t)B * N * sizeof(int));
    int*   ssrc    = (int*)alloc((size_t)B * E * sizeof(int));
    float* pooled  = (float*)alloc((size_t)B * H * sizeof(float));
    unsigned short* bufA = (unsigned short*)alloc((size_t)B * N * H * 2);
    unsigned short* bufB = (unsigned short*)alloc((size_t)B * N * H * 2);

    ConvArgs ca;
    ca.src[0] = x;        ca.dst[0] = (float*)pooled;  // unused dst slot
    ca.src[1] = d_in[3];  ca.dst[1] = W1f;
    ca.src[2] = d_in[4];  ca.dst[2] = b1f;
    ca.src[3] = d_in[5];  ca.dst[3] = W2f;
    ca.src[4] = d_in[6];  ca.dst[4] = b2f_;
    ca.src[5] = d_in[7];  ca.dst[5] = aW1f;
    ca.src[6] = d_in[8];  ca.dst[6] = ab1f;
    ca.src[7] = d_in[9];  ca.dst[7] = aW2f;
    ca.src[8] = d_in[10]; ca.dst[8] = ab2f;

    k_flags<<<10, 256, 0, stream>>>(ca, mask, flags);
    k_convert_small<<<8, 256, 0, stream>>>(ca, flags);
    k_compute_n<<<B, 256, 0, stream>>>(mask, flags, n_arr);
    k_zero2<<<(B * N + B * H + 255) / 256, 256, 0, stream>>>(count, pooled);
    k_count<<<(B * E) / 256, 256, 0, stream>>>(eidx, n_arr, count);
    k_scan<<<B, 256, 0, stream>>>(count, n_arr, offsets, cursor, dis);
    k_fill<<<(B * E) / 256, 256, 0, stream>>>(eidx, n_arr, cursor, ssrc);

    // Layer 1 (x read directly; dtype branch on flags[0])
    k_gemm<F><<<(B * N) / 64, 256, 0, stream>>>(x, flags + 0, W1f, bufA);
    k_aggregate<<<(B * N) / 4, 256, 0, stream>>>(bufA, dis, offsets, count, ssrc, b1f, bufB);
    // Layer 2 (bufB is always bf16; flags[10] == 1)
    k_gemm<H><<<(B * N) / 64, 256, 0, stream>>>(bufB, flags + 10, W2f, bufA);
    k_aggregate<<<(B * N) / 4, 256, 0, stream>>>(bufA, dis, offsets, count, ssrc, b2f_, bufB);
    // Pool + head
    k_pool_partial<<<B * 4, 256, 0, stream>>>(bufB, pooled);
    k_mlp<<<B, 64, 0, stream>>>(pooled, n_arr, aW1f, ab1f, aW2f, ab2f, flags, d_out);
}

// Round 4
// 403.368 us; speedup vs baseline: 1.7801x; 1.1822x over previous
//
#include <hip/hip_runtime.h>
#include <hip/hip_bf16.h>

#define B 128
#define N 2048
#define E 16384
#define F 32
#define H 64
#define OUTD 16
#define CAP 32

__device__ __forceinline__ float b2f(unsigned short u) {
    return __uint_as_float(((unsigned int)u) << 16);
}
__device__ __forceinline__ unsigned short f2b(float f) {
    unsigned int x = __float_as_uint(f);
    unsigned int r = (x + 0x7FFFu + ((x >> 16) & 1u)) >> 16;  // RNE, finite
    return (unsigned short)r;
}

struct PrepArgs {
    const void* src[9];
    float* dst[9];
};

// ---------------------------------------------------------------------------
// K0 (fused prep): blocks 0..8 — per-array local dtype probe (bf16 vs f32 by
// magnitude statistics) + convert weights (1..8) to f32; block 0 only writes
// flags[0] (x consumed directly by GEMM1). Blocks 9..9+B-1 — mask-encoding
// probe (mask[0..1] always true since n>=1024) + per-batch nonzero count.
// ---------------------------------------------------------------------------
__global__ __launch_bounds__(256) void k_prep(PrepArgs pa, const void* mask,
                                              int* flags, int* n_arr) {
    const int bid = blockIdx.x;
    const int t = threadIdx.x;
    if (bid < 9) {
        int sz;
        switch (bid) {
            case 0: sz = B * N * F; break;
            case 1: sz = F * H; break;
            case 2: sz = H; break;
            case 3: sz = H * H; break;
            case 4: sz = H; break;
            case 5: sz = H * H; break;
            case 6: sz = H; break;
            case 7: sz = H * OUTD; break;
            default: sz = OUTD; break;
        }
        const int K = sz < 1024 ? sz : 1024;
        const unsigned short* p = (const unsigned short*)pa.src[bid];
        float s = 0.f;
        for (int i = t; i < K; i += 256) s += fminf(fabsf(b2f(p[i])), 1e6f);
        __shared__ float red[256];
        __shared__ int isbf;
        red[t] = s;
        __syncthreads();
        for (int st = 128; st > 0; st >>= 1) {
            if (t < st) red[t] += red[t + st];
            __syncthreads();
        }
        if (t == 0) {
            int f = (red[0] < 100.0f * (float)K) ? 1 : 0;
            isbf = f;
            if (bid == 0) flags[0] = f;
        }
        __syncthreads();
        if (bid == 0) return;
        const int fl = isbf;
        float* dst = pa.dst[bid];
        for (int i = t; i < sz; i += 256)
            dst[i] = fl ? b2f(((const unsigned short*)pa.src[bid])[i])
                        : ((const float*)pa.src[bid])[i];
        return;
    }
    // mask blocks
    const int b = bid - 9;
    const unsigned char* mb = (const unsigned char*)mask;
    int mode;
    if (mb[0] == 0x80 && mb[1] == 0x3F) mode = 2;        // bf16
    else if (mb[0] != 0 && mb[1] != 0) mode = 0;         // bytes
    else if (mb[0] != 0) mode = (mb[4] != 0) ? 1 : 4;    // int32 : int64
    else mode = 3;                                       // f32
    if (b == 0 && t == 0) { flags[9] = mode; flags[10] = 1; }
    int cnt = 0;
    if (mode == 0) {
        const unsigned char* r = mb + (size_t)b * N;
        for (int i = t; i < N; i += 256) cnt += (r[i] != 0);
    } else if (mode == 1 || mode == 3) {
        const unsigned int* r = (const unsigned int*)mask + (size_t)b * N;
        for (int i = t; i < N; i += 256) cnt += (r[i] != 0);
    } else if (mode == 2) {
        const unsigned short* r = (const unsigned short*)mask + (size_t)b * N;
        for (int i = t; i < N; i += 256) cnt += (r[i] != 0);
    } else {
        const unsigned long long* r = (const unsigned long long*)mask + (size_t)b * N;
        for (int i = t; i < N; i += 256) cnt += (r[i] != 0ULL);
    }
    __shared__ int sdata[256];
    sdata[t] = cnt;
    __syncthreads();
    for (int s = 128; s > 0; s >>= 1) {
        if (t < s) sdata[t] += sdata[t + s];
        __syncthreads();
    }
    if (t == 0) {
        int n = sdata[0];
        n_arr[b] = (n > N) ? N : n;
    }
}

// ---------------------------------------------------------------------------
// K1: zero cnt (B*N), ovf_cnt (B), pooled (B*H)
// ---------------------------------------------------------------------------
__global__ __launch_bounds__(256) void k_zero(int* __restrict__ cnt,
                                              int* __restrict__ ovf_cnt,
                                              float* __restrict__ pooled) {
    const int i = blockIdx.x * 256 + threadIdx.x;
    if (i < B * N) cnt[i] = 0;
    if (i < B) ovf_cnt[i] = 0;
    if (i < B * H) pooled[i] = 0.0f;
}

// ---------------------------------------------------------------------------
// K2: capacity-CSR fill in ONE pass. cnt[dst]++ gives slot AND final degree.
// deg>CAP spills to per-batch overflow list (handled in k_agg; ~never taken).
// ---------------------------------------------------------------------------
__global__ __launch_bounds__(256) void k_fill(const int* __restrict__ eidx,
                                              const int* __restrict__ n_arr,
                                              int* __restrict__ cnt,
                                              int* __restrict__ ssrc,
                                              int2* __restrict__ ovf,
                                              int* __restrict__ ovf_cnt) {
    const int i = blockIdx.x * 256 + threadIdx.x;
    const int b = i >> 14;
    const int e = i & (E - 1);
    const int n = n_arr[b];
    const int src = eidx[(size_t)b * 2 * E + e];
    const int dst = eidx[(size_t)b * 2 * E + E + e];
    if ((unsigned)src < (unsigned)n && (unsigned)dst < (unsigned)n) {
        int pos = atomicAdd(&cnt[b * N + dst], 1);
        if (pos < CAP) ssrc[((size_t)(b * N + dst)) * CAP + pos] = src;
        else {
            int oi = atomicAdd(&ovf_cnt[b], 1);
            if ((unsigned)oi < (unsigned)E) ovf[(size_t)b * E + oi] = make_int2(dst, src);
        }
    }
}

// ---------------------------------------------------------------------------
// K3: GEMM out = in @ W. 64 rows/block, thread computes 4 rows x 4 cols.
// ---------------------------------------------------------------------------
template <int FIN>
__global__ __launch_bounds__(256) void k_gemm(const void* __restrict__ in,
                                              const int* __restrict__ bf16flag,
                                              const float* __restrict__ W,
                                              unsigned short* __restrict__ out) {
    __shared__ float As[64][FIN + 4];
    __shared__ float Ws[FIN * H];
    const int tid = threadIdx.x;
    for (int i = tid; i < FIN * H; i += 256) Ws[i] = W[i];
    const size_t row0 = (size_t)blockIdx.x * 64;
    const int total = 64 * FIN;
    if (*bf16flag) {
        const unsigned short* ip = (const unsigned short*)in + row0 * FIN;
        for (int i = tid * 4; i < total; i += 1024) {
            ushort4 u = *(const ushort4*)(ip + i);
            int r = i / FIN, f = i & (FIN - 1);
            As[r][f] = b2f(u.x); As[r][f + 1] = b2f(u.y);
            As[r][f + 2] = b2f(u.z); As[r][f + 3] = b2f(u.w);
        }
    } else {
        const float* ip = (const float*)in + row0 * FIN;
        for (int i = tid * 4; i < total; i += 1024) {
            float4 u = *(const float4*)(ip + i);
            int r = i / FIN, f = i & (FIN - 1);
            As[r][f] = u.x; As[r][f + 1] = u.y;
            As[r][f + 2] = u.z; As[r][f + 3] = u.w;
        }
    }
    __syncthreads();
    const int r0 = (tid >> 4) * 4;
    const int cg = (tid & 15) * 4;
    float acc[4][4] = {};
    for (int f = 0; f < FIN; f++) {
        float4 w = *(const float4*)&Ws[f * H + cg];
#pragma unroll
        for (int rr = 0; rr < 4; rr++) {
            float a = As[r0 + rr][f];
            acc[rr][0] += a * w.x; acc[rr][1] += a * w.y;
            acc[rr][2] += a * w.z; acc[rr][3] += a * w.w;
        }
    }
#pragma unroll
    for (int rr = 0; rr < 4; rr++) {
        ushort4 o;
        o.x = f2b(acc[rr][0]); o.y = f2b(acc[rr][1]);
        o.z = f2b(acc[rr][2]); o.w = f2b(acc[rr][3]);
        *(ushort4*)&out[(row0 + r0 + rr) * H + cg] = o;
    }
}

// ---------------------------------------------------------------------------
// K4: aggregation v3. Block = 64 nodes of one batch; cnt[b,:] staged in LDS
// (dis = rsqrt(cnt+1) becomes LDS broadcast + VALU). Wave processes 16 nodes
// sequentially with next-node ssrc prefetch (cross-node MLP).
// out[v,f] = relu(dv*(dv*hW[v,f] + sum_s dis_s*hW[s,f]) + bias[f]); 0 invalid.
// ---------------------------------------------------------------------------
__global__ __launch_bounds__(256) void k_agg(
    const unsigned short* __restrict__ hW, const int* __restrict__ cnt,
    const int* __restrict__ n_arr, const int* __restrict__ ssrc,
    const int2* __restrict__ ovf, const int* __restrict__ ovf_cnt,
    const float* __restrict__ bias, unsigned short* __restrict__ outb) {
    __shared__ int s_cnt[N];
    const int bid = blockIdx.x;      // B*32 blocks
    const int b = bid >> 5;
    const int v0 = (bid & 31) * 64;
    const int t = threadIdx.x;
    const int bN = b * N;
    {   // stage cnt[b,:] -> LDS (2048 ints, int4-vectorized)
        const int4* g = (const int4*)(cnt + bN);
        int4* s = (int4*)s_cnt;
        s[t] = g[t];
        s[t + 256] = g[t + 256];
    }
    __syncthreads();
    const int n = n_arr[b];
    const int lane = t & 63;
    const int w = t >> 6;
    const float bi = bias[lane];
    const int oc = ovf_cnt[b];

    int v = v0 + w * 16;
    int deg = s_cnt[v];
    int pidx = (lane < CAP) ? ssrc[((size_t)(bN + v)) * CAP + lane] : 0;
    if (lane >= deg) pidx = 0;

    for (int k = 0; k < 16; k++, v++) {
        const int degc = deg < CAP ? deg : CAP;
        float self = b2f(hW[(size_t)(bN + v) * H + lane]);
        // prefetch next node's indices (hides ssrc latency under gathers)
        int ndeg = 0, npidx = 0;
        if (k < 15) {
            ndeg = s_cnt[v + 1];
            npidx = (lane < CAP) ? ssrc[((size_t)(bN + v + 1)) * CAP + lane] : 0;
            if (lane >= ndeg) npidx = 0;
        }
        const float dv = (v < n) ? rsqrtf((float)(deg + 1)) : 0.0f;
        float acc = dv * self;
        int i = 0;
        for (; i + 4 <= degc; i += 4) {
            int s0 = __shfl(pidx, i);     int s1 = __shfl(pidx, i + 1);
            int s2 = __shfl(pidx, i + 2); int s3 = __shfl(pidx, i + 3);
            float h0 = b2f(hW[(size_t)(bN + s0) * H + lane]);
            float h1 = b2f(hW[(size_t)(bN + s1) * H + lane]);
            float h2 = b2f(hW[(size_t)(bN + s2) * H + lane]);
            float h3 = b2f(hW[(size_t)(bN + s3) * H + lane]);
            float d0 = rsqrtf((float)(s_cnt[s0] + 1));
            float d1 = rsqrtf((float)(s_cnt[s1] + 1));
            float d2 = rsqrtf((float)(s_cnt[s2] + 1));
            float d3 = rsqrtf((float)(s_cnt[s3] + 1));
            acc = fmaf(d0, h0, acc); acc = fmaf(d1, h1, acc);
            acc = fmaf(d2, h2, acc); acc = fmaf(d3, h3, acc);
        }
        for (; i < degc; i++) {
            int s = __shfl(pidx, i);
            acc = fmaf(rsqrtf((float)(s_cnt[s] + 1)),
                       b2f(hW[(size_t)(bN + s) * H + lane]), acc);
        }
        if (oc > 0) {  // overflow slow path (deg > CAP spills) — ~never taken
            for (int j = 0; j < oc && j < E; j++) {
                int2 ov = ovf[(size_t)b * E + j];
                if (ov.x == v)
                    acc = fmaf(rsqrtf((float)(s_cnt[ov.y] + 1)),
                               b2f(hW[(size_t)(bN + ov.y) * H + lane]), acc);
            }
        }
        float res = (v < n) ? fmaxf(fmaf(dv, acc, bi), 0.0f) : 0.0f;
        outb[(size_t)(bN + v) * H + lane] = f2b(res);
        deg = ndeg;
        pidx = npidx;
    }
}

// ---------------------------------------------------------------------------
// K5: parallel pool partials (B*4 blocks) -> atomicAdd into pooled
// ---------------------------------------------------------------------------
__global__ __launch_bounds__(256) void k_pool_partial(
    const unsigned short* __restrict__ h2, float* __restrict__ pooled) {
    const int b = blockIdx.x >> 2;
    const int chunk = blockIdx.x & 3;
    const int f = threadIdx.x & 63;
    const int w = threadIdx.x >> 6;
    const unsigned short* hb = h2 + ((size_t)b * N + chunk * 512) * H;
    float s = 0.0f;
    for (int v = w; v < 512; v += 4) s += b2f(hb[(size_t)v * H + f]);
    __shared__ float red[4][64];
    red[w][f] = s;
    __syncthreads();
    if (w == 0)
        atomicAdd(&pooled[b * H + f],
                  red[0][f] + red[1][f] + red[2][f] + red[3][f]);
}

// ---------------------------------------------------------------------------
// K6: MLP head, one wave per batch.
// ---------------------------------------------------------------------------
__global__ __launch_bounds__(64) void k_mlp(
    const float* __restrict__ pooled, const int* __restrict__ n_arr,
    const float* __restrict__ aW1, const float* __restrict__ ab1,
    const float* __restrict__ aW2, const float* __restrict__ ab2,
    const int* __restrict__ flags, void* __restrict__ out) {
    const int b = blockIdx.x;
    const int t = threadIdx.x;
    __shared__ float p[64];
    __shared__ float hid[64];
    int n = n_arr[b];
    if (n < 1) n = 1;
    p[t] = pooled[b * H + t] / (float)n;
    __syncthreads();
    float acc = ab1[t];
    for (int j = 0; j < 64; j++) acc += p[j] * aW1[j * 64 + t];
    hid[t] = fmaxf(acc, 0.0f);
    __syncthreads();
    if (t < 16) {
        float a2 = ab2[t];
        for (int j = 0; j < 64; j++) a2 += hid[j] * aW2[j * 16 + t];
        if (flags[0]) ((unsigned short*)out)[b * OUTD + t] = f2b(a2);
        else          ((float*)out)[b * OUTD + t] = a2;
    }
}

// ---------------------------------------------------------------------------
extern "C" void kernel_launch(void* const* d_in, const int* in_sizes, int n_in,
                              void* d_out, int out_size, void* d_ws, size_t ws_size,
                              hipStream_t stream) {
    const void* x    = d_in[0];
    const int*  eidx = (const int*)d_in[1];
    const void* mask = d_in[2];

    char* ws = (char*)d_ws;
    size_t off = 0;
    auto alloc = [&](size_t bytes) -> void* {
        void* p = ws + off;
        off += (bytes + 255) & ~(size_t)255;
        return p;
    };
    int*   flags   = (int*)alloc(16 * sizeof(int));
    float* W1f     = (float*)alloc(F * H * sizeof(float));
    float* b1f     = (float*)alloc(H * sizeof(float));
    float* W2f     = (float*)alloc(H * H * sizeof(float));
    float* b2f_    = (float*)alloc(H * sizeof(float));
    float* aW1f    = (float*)alloc(H * H * sizeof(float));
    float* ab1f    = (float*)alloc(H * sizeof(float));
    float* aW2f    = (float*)alloc(H * OUTD * sizeof(float));
    float* ab2f    = (float*)alloc(OUTD * sizeof(float));
    int*   n_arr   = (int*)alloc(B * sizeof(int));
    int*   cnt     = (int*)alloc((size_t)B * N * sizeof(int));
    int*   ovf_cnt = (int*)alloc(B * sizeof(int));
    int*   ssrc    = (int*)alloc((size_t)B * N * CAP * sizeof(int));
    int2*  ovf     = (int2*)alloc((size_t)B * E * sizeof(int2));
    float* pooled  = (float*)alloc((size_t)B * H * sizeof(float));
    unsigned short* bufA = (unsigned short*)alloc((size_t)B * N * H * 2);
    unsigned short* bufB = (unsigned short*)alloc((size_t)B * N * H * 2);

    PrepArgs pa;
    pa.src[0] = x;        pa.dst[0] = pooled;  // dst[0] unused
    pa.src[1] = d_in[3];  pa.dst[1] = W1f;
    pa.src[2] = d_in[4];  pa.dst[2] = b1f;
    pa.src[3] = d_in[5];  pa.dst[3] = W2f;
    pa.src[4] = d_in[6];  pa.dst[4] = b2f_;
    pa.src[5] = d_in[7];  pa.dst[5] = aW1f;
    pa.src[6] = d_in[8];  pa.dst[6] = ab1f;
    pa.src[7] = d_in[9];  pa.dst[7] = aW2f;
    pa.src[8] = d_in[10]; pa.dst[8] = ab2f;

    k_prep<<<9 + B, 256, 0, stream>>>(pa, mask, flags, n_arr);
    k_zero<<<(B * N + 255) / 256, 256, 0, stream>>>(cnt, ovf_cnt, pooled);
    k_fill<<<(B * E) / 256, 256, 0, stream>>>(eidx, n_arr, cnt, ssrc, ovf, ovf_cnt);

    // Layer 1
    k_gemm<F><<<(B * N) / 64, 256, 0, stream>>>(x, flags + 0, W1f, bufA);
    k_agg<<<B * 32, 256, 0, stream>>>(bufA, cnt, n_arr, ssrc, ovf, ovf_cnt, b1f, bufB);
    // Layer 2
    k_gemm<H><<<(B * N) / 64, 256, 0, stream>>>(bufB, flags + 10, W2f, bufA);
    k_agg<<<B * 32, 256, 0, stream>>>(bufA, cnt, n_arr, ssrc, ovf, ovf_cnt, b2f_, bufB);
    // Pool + head
    k_pool_partial<<<B * 4, 256, 0, stream>>>(bufB, pooled);
    k_mlp<<<B, 64, 0, stream>>>(pooled, n_arr, aW1f, ab1f, aW2f, ab2f, flags, d_out);
}

// Round 5
// 342.535 us; speedup vs baseline: 2.0962x; 1.1776x over previous
//
#include <hip/hip_runtime.h>
#include <hip/hip_bf16.h>

#define B 128
#define N 2048
#define E 16384
#define F 32
#define H 64
#define OUTD 16
#define CAP 16

__device__ __forceinline__ float b2f(unsigned short u) {
    return __uint_as_float(((unsigned int)u) << 16);
}
__device__ __forceinline__ unsigned short f2b(float f) {
    unsigned int x = __float_as_uint(f);
    unsigned int r = (x + 0x7FFFu + ((x >> 16) & 1u)) >> 16;  // RNE, finite
    return (unsigned short)r;
}

struct PrepArgs {
    const void* src[9];
    float* dst[9];
};

// ---------------------------------------------------------------------------
// K0: prep. Block 0: probe x dtype -> flags[0], set flags[10]=1.
// Blocks 1..8: probe + convert weight arrays to f32.
// ---------------------------------------------------------------------------
__global__ __launch_bounds__(256) void k_prep(PrepArgs pa, int* flags) {
    const int bid = blockIdx.x;
    const int t = threadIdx.x;
    int sz;
    switch (bid) {
        case 0: sz = B * N * F; break;
        case 1: sz = F * H; break;
        case 2: sz = H; break;
        case 3: sz = H * H; break;
        case 4: sz = H; break;
        case 5: sz = H * H; break;
        case 6: sz = H; break;
        case 7: sz = H * OUTD; break;
        default: sz = OUTD; break;
    }
    const int K = sz < 1024 ? sz : 1024;
    const unsigned short* p = (const unsigned short*)pa.src[bid];
    float s = 0.f;
    for (int i = t; i < K; i += 256) s += fminf(fabsf(b2f(p[i])), 1e6f);
    __shared__ float red[256];
    __shared__ int isbf;
    red[t] = s;
    __syncthreads();
    for (int st = 128; st > 0; st >>= 1) {
        if (t < st) red[t] += red[t + st];
        __syncthreads();
    }
    if (t == 0) {
        int f = (red[0] < 100.0f * (float)K) ? 1 : 0;
        isbf = f;
        if (bid == 0) { flags[0] = f; flags[10] = 1; }
    }
    __syncthreads();
    if (bid == 0) return;
    const int fl = isbf;
    float* dst = pa.dst[bid];
    for (int i = t; i < sz; i += 256)
        dst[i] = fl ? b2f(((const unsigned short*)pa.src[bid])[i])
                    : ((const float*)pa.src[bid])[i];
}

// ---------------------------------------------------------------------------
// K1: per-batch graph build. One block per batch; cnt lives in LDS.
// Two passes over the batch's edge slice (2nd pass L2-hot). Emits: n_arr,
// dis (f32), degc (uchar, min(deg,CAP)), ssrc (ushort capacity-CSR),
// overflow list (deg>CAP; unconditionally correct). Zeroes pooled.
// ---------------------------------------------------------------------------
__global__ __launch_bounds__(256) void k_build(
    const int* __restrict__ eidx, const void* __restrict__ mask,
    int* __restrict__ n_arr, float* __restrict__ dis,
    unsigned char* __restrict__ degc, unsigned short* __restrict__ ssrc,
    int2* __restrict__ ovf, int* __restrict__ ovf_cnt,
    float* __restrict__ pooled) {
    __shared__ int s_cnt[N];
    __shared__ int s_red[256];
    __shared__ int s_n;
    __shared__ int s_ovf;
    const int b = blockIdx.x;
    const int t = threadIdx.x;
    const int bN = b * N;
    // mask mode detect (uniform) + count n
    const unsigned char* mb = (const unsigned char*)mask;
    int mode;
    if (mb[0] == 0x80 && mb[1] == 0x3F) mode = 2;        // bf16
    else if (mb[0] != 0 && mb[1] != 0) mode = 0;         // bytes
    else if (mb[0] != 0) mode = (mb[4] != 0) ? 1 : 4;    // int32 : int64
    else mode = 3;                                       // f32
    int cnt = 0;
    if (mode == 0) {
        const unsigned char* r = mb + (size_t)b * N;
        for (int i = t; i < N; i += 256) cnt += (r[i] != 0);
    } else if (mode == 1 || mode == 3) {
        const unsigned int* r = (const unsigned int*)mask + (size_t)b * N;
        for (int i = t; i < N; i += 256) cnt += (r[i] != 0);
    } else if (mode == 2) {
        const unsigned short* r = (const unsigned short*)mask + (size_t)b * N;
        for (int i = t; i < N; i += 256) cnt += (r[i] != 0);
    } else {
        const unsigned long long* r = (const unsigned long long*)mask + (size_t)b * N;
        for (int i = t; i < N; i += 256) cnt += (r[i] != 0ULL);
    }
    s_red[t] = cnt;
    for (int i = t; i < N; i += 256) s_cnt[i] = 0;
    if (t == 0) s_ovf = 0;
    __syncthreads();
    if (t < 128) s_red[t] += s_red[t + 128];
    __syncthreads();
    if (t < 64) s_red[t] += s_red[t + 64];
    __syncthreads();
    if (t == 0) {
        int acc = 0;
        for (int i = 0; i < 64; i++) acc += s_red[i];
        s_n = acc > N ? N : acc;
    }
    __syncthreads();
    const int n = s_n;
    const int* es = eidx + (size_t)b * 2 * E;
    const int* ed = es + E;
    // pass 1: count
    for (int i = t; i < E; i += 256) {
        int src = es[i], dst = ed[i];
        if ((unsigned)src < (unsigned)n && (unsigned)dst < (unsigned)n)
            atomicAdd(&s_cnt[dst], 1);
    }
    __syncthreads();
    // dis/degc emit + cursor reset
    for (int v = t; v < N; v += 256) {
        int c = s_cnt[v];
        dis[bN + v] = (v < n) ? rsqrtf((float)(c + 1)) : 0.0f;
        degc[bN + v] = (unsigned char)(c < CAP ? c : CAP);
        s_cnt[v] = 0;
    }
    __syncthreads();
    // pass 2: fill (edge slice is L2-hot now)
    for (int i = t; i < E; i += 256) {
        int src = es[i], dst = ed[i];
        if ((unsigned)src < (unsigned)n && (unsigned)dst < (unsigned)n) {
            int pos = atomicAdd(&s_cnt[dst], 1);
            if (pos < CAP)
                ssrc[((size_t)(bN + dst)) * CAP + pos] = (unsigned short)src;
            else {
                int oi = atomicAdd(&s_ovf, 1);
                ovf[(size_t)b * E + oi] = make_int2(dst, src);
            }
        }
    }
    if (t == 0) { n_arr[b] = n; ovf_cnt[b] = s_ovf; }
    if (t < H) pooled[b * H + t] = 0.0f;
}

// ---------------------------------------------------------------------------
// K2: GEMM out = in @ W. 64 rows/block, thread computes 4 rows x 4 cols.
// ---------------------------------------------------------------------------
template <int FIN>
__global__ __launch_bounds__(256) void k_gemm(const void* __restrict__ in,
                                              const int* __restrict__ bf16flag,
                                              const float* __restrict__ W,
                                              unsigned short* __restrict__ out) {
    __shared__ float As[64][FIN + 4];
    __shared__ float Ws[FIN * H];
    const int tid = threadIdx.x;
    for (int i = tid; i < FIN * H; i += 256) Ws[i] = W[i];
    const size_t row0 = (size_t)blockIdx.x * 64;
    const int total = 64 * FIN;
    if (*bf16flag) {
        const unsigned short* ip = (const unsigned short*)in + row0 * FIN;
        for (int i = tid * 4; i < total; i += 1024) {
            ushort4 u = *(const ushort4*)(ip + i);
            int r = i / FIN, f = i & (FIN - 1);
            As[r][f] = b2f(u.x); As[r][f + 1] = b2f(u.y);
            As[r][f + 2] = b2f(u.z); As[r][f + 3] = b2f(u.w);
        }
    } else {
        const float* ip = (const float*)in + row0 * FIN;
        for (int i = tid * 4; i < total; i += 1024) {
            float4 u = *(const float4*)(ip + i);
            int r = i / FIN, f = i & (FIN - 1);
            As[r][f] = u.x; As[r][f + 1] = u.y;
            As[r][f + 2] = u.z; As[r][f + 3] = u.w;
        }
    }
    __syncthreads();
    const int r0 = (tid >> 4) * 4;
    const int cg = (tid & 15) * 4;
    float acc[4][4] = {};
    for (int f = 0; f < FIN; f++) {
        float4 w = *(const float4*)&Ws[f * H + cg];
#pragma unroll
        for (int rr = 0; rr < 4; rr++) {
            float a = As[r0 + rr][f];
            acc[rr][0] += a * w.x; acc[rr][1] += a * w.y;
            acc[rr][2] += a * w.z; acc[rr][3] += a * w.w;
        }
    }
#pragma unroll
    for (int rr = 0; rr < 4; rr++) {
        ushort4 o;
        o.x = f2b(acc[rr][0]); o.y = f2b(acc[rr][1]);
        o.z = f2b(acc[rr][2]); o.w = f2b(acc[rr][3]);
        *(ushort4*)&out[(row0 + r0 + rr) * H + cg] = o;
    }
}

// ---------------------------------------------------------------------------
// K3: aggregation v4, slim. Block = 64 nodes; per-block LDS: dis row (8 KB),
// edge slice (2 KB ushort), degc (64 B). Inner loop per edge:
// ds_read_u16 (idx, broadcast) + ds_read_b32 (dis) + lshl_add + load + fma.
// MODE 0: store relu row (bf16). MODE 1: accumulate pooled sum (h2 never
// materialized).
// ---------------------------------------------------------------------------
template <int MODE>
__global__ __launch_bounds__(256) void k_agg(
    const unsigned short* __restrict__ hW, const float* __restrict__ dis,
    const unsigned char* __restrict__ degc, const unsigned short* __restrict__ ssrc,
    const int2* __restrict__ ovf, const int* __restrict__ ovf_cnt,
    const float* __restrict__ bias, unsigned short* __restrict__ outb,
    float* __restrict__ pooled) {
    __shared__ float s_dis[N];
    __shared__ unsigned short s_e[64 * CAP];
    __shared__ unsigned char s_dg[64];
    __shared__ float s_red[4][64];
    const int bid = blockIdx.x;  // B*32
    const int b = bid >> 5;
    const int v0 = (bid & 31) * 64;
    const int t = threadIdx.x;
    const int bN = b * N;
    {   // stage dis row: 512 float4
        const float4* g = (const float4*)(dis + bN);
        float4* s = (float4*)s_dis;
        s[t] = g[t];
        s[t + 256] = g[t + 256];
    }
    if (t < 128) {  // stage edge slice: 128 int4 = 1024 ushort
        ((int4*)s_e)[t] = ((const int4*)(ssrc + (size_t)(bN + v0) * CAP))[t];
    }
    if (t < 16) {   // stage degc: 16 uints = 64 bytes
        ((unsigned int*)s_dg)[t] = ((const unsigned int*)(degc + bN + v0))[t];
    }
    __syncthreads();
    const int lane = t & 63;
    const int w = t >> 6;
    const float bi = bias[lane];
    const int oc = ovf_cnt[b];
    const unsigned short* hWb = hW + (size_t)bN * H;
    float psum = 0.0f;
    int v = v0 + w * 16;
    for (int k = 0; k < 16; k++, v++) {
        const int nn = w * 16 + k;
        const int dg = s_dg[nn];
        const float dv = s_dis[v];
        float acc = dv * b2f(hWb[(v << 6) + lane]);
        const unsigned short* ep = &s_e[nn * CAP];
        int i = 0;
        for (; i + 2 <= dg; i += 2) {
            int i0 = ep[i], i1 = ep[i + 1];
            float h0 = b2f(hWb[(i0 << 6) + lane]);
            float h1 = b2f(hWb[(i1 << 6) + lane]);
            acc = fmaf(s_dis[i0], h0, acc);
            acc = fmaf(s_dis[i1], h1, acc);
        }
        if (i < dg) {
            int i0 = ep[i];
            acc = fmaf(s_dis[i0], b2f(hWb[(i0 << 6) + lane]), acc);
        }
        if (oc > 0) {  // deg>CAP spill path; ~never taken
            const int2* ob = ovf + (size_t)b * E;
            for (int j = 0; j < oc; j++) {
                int2 o = ob[j];
                if (o.x == v)
                    acc = fmaf(s_dis[o.y], b2f(hWb[(o.y << 6) + lane]), acc);
            }
        }
        float res = (dv > 0.0f) ? fmaxf(fmaf(dv, acc, bi), 0.0f) : 0.0f;
        if (MODE == 0) outb[(size_t)((bN + v) << 6) + lane] = f2b(res);
        else psum += res;
    }
    if (MODE == 1) {
        s_red[w][lane] = psum;
        __syncthreads();
        if (w == 0)
            atomicAdd(&pooled[b * H + lane],
                      s_red[0][lane] + s_red[1][lane] + s_red[2][lane] + s_red[3][lane]);
    }
}

// ---------------------------------------------------------------------------
// K4: MLP head, one wave per batch.
// ---------------------------------------------------------------------------
__global__ __launch_bounds__(64) void k_mlp(
    const float* __restrict__ pooled, const int* __restrict__ n_arr,
    const float* __restrict__ aW1, const float* __restrict__ ab1,
    const float* __restrict__ aW2, const float* __restrict__ ab2,
    const int* __restrict__ flags, void* __restrict__ out) {
    const int b = blockIdx.x;
    const int t = threadIdx.x;
    __shared__ float p[64];
    __shared__ float hid[64];
    int n = n_arr[b];
    if (n < 1) n = 1;
    p[t] = pooled[b * H + t] / (float)n;
    __syncthreads();
    float acc = ab1[t];
    for (int j = 0; j < 64; j++) acc += p[j] * aW1[j * 64 + t];
    hid[t] = fmaxf(acc, 0.0f);
    __syncthreads();
    if (t < 16) {
        float a2 = ab2[t];
        for (int j = 0; j < 64; j++) a2 += hid[j] * aW2[j * 16 + t];
        if (flags[0]) ((unsigned short*)out)[b * OUTD + t] = f2b(a2);
        else          ((float*)out)[b * OUTD + t] = a2;
    }
}

// ---------------------------------------------------------------------------
extern "C" void kernel_launch(void* const* d_in, const int* in_sizes, int n_in,
                              void* d_out, int out_size, void* d_ws, size_t ws_size,
                              hipStream_t stream) {
    const void* x    = d_in[0];
    const int*  eidx = (const int*)d_in[1];
    const void* mask = d_in[2];

    char* ws = (char*)d_ws;
    size_t off = 0;
    auto alloc = [&](size_t bytes) -> void* {
        void* p = ws + off;
        off += (bytes + 255) & ~(size_t)255;
        return p;
    };
    int*   flags   = (int*)alloc(16 * sizeof(int));
    float* W1f     = (float*)alloc(F * H * sizeof(float));
    float* b1f     = (float*)alloc(H * sizeof(float));
    float* W2f     = (float*)alloc(H * H * sizeof(float));
    float* b2f_    = (float*)alloc(H * sizeof(float));
    float* aW1f    = (float*)alloc(H * H * sizeof(float));
    float* ab1f    = (float*)alloc(H * sizeof(float));
    float* aW2f    = (float*)alloc(H * OUTD * sizeof(float));
    float* ab2f    = (float*)alloc(OUTD * sizeof(float));
    int*   n_arr   = (int*)alloc(B * sizeof(int));
    float* dis     = (float*)alloc((size_t)B * N * sizeof(float));
    unsigned char*  degc = (unsigned char*)alloc((size_t)B * N);
    unsigned short* ssrc = (unsigned short*)alloc((size_t)B * N * CAP * 2);
    int2*  ovf     = (int2*)alloc((size_t)B * E * sizeof(int2));
    int*   ovf_cnt = (int*)alloc(B * sizeof(int));
    float* pooled  = (float*)alloc((size_t)B * H * sizeof(float));
    unsigned short* bufA = (unsigned short*)alloc((size_t)B * N * H * 2);
    unsigned short* bufB = (unsigned short*)alloc((size_t)B * N * H * 2);

    PrepArgs pa;
    pa.src[0] = x;        pa.dst[0] = pooled;  // dst[0] unused
    pa.src[1] = d_in[3];  pa.dst[1] = W1f;
    pa.src[2] = d_in[4];  pa.dst[2] = b1f;
    pa.src[3] = d_in[5];  pa.dst[3] = W2f;
    pa.src[4] = d_in[6];  pa.dst[4] = b2f_;
    pa.src[5] = d_in[7];  pa.dst[5] = aW1f;
    pa.src[6] = d_in[8];  pa.dst[6] = ab1f;
    pa.src[7] = d_in[9];  pa.dst[7] = aW2f;
    pa.src[8] = d_in[10]; pa.dst[8] = ab2f;

    k_prep<<<9, 256, 0, stream>>>(pa, flags);
    k_build<<<B, 256, 0, stream>>>(eidx, mask, n_arr, dis, degc, ssrc, ovf,
                                   ovf_cnt, pooled);
    // Layer 1: hW1 = x @ W1 ; h1 = agg(hW1) stored bf16
    k_gemm<F><<<(B * N) / 64, 256, 0, stream>>>(x, flags + 0, W1f, bufA);
    k_agg<0><<<B * 32, 256, 0, stream>>>(bufA, dis, degc, ssrc, ovf, ovf_cnt,
                                         b1f, bufB, pooled);
    // Layer 2: hW2 = h1 @ W2 ; agg fused with pooling (h2 never stored)
    k_gemm<H><<<(B * N) / 64, 256, 0, stream>>>(bufB, flags + 10, W2f, bufA);
    k_agg<1><<<B * 32, 256, 0, stream>>>(bufA, dis, degc, ssrc, ovf, ovf_cnt,
                                         b2f_, nullptr, pooled);
    // Head
    k_mlp<<<B, 64, 0, stream>>>(pooled, n_arr, aW1f, ab1f, aW2f, ab2f, flags, d_out);
}

// Round 6
// 315.731 us; speedup vs baseline: 2.2742x; 1.0849x over previous
//
#include <hip/hip_runtime.h>
#include <hip/hip_bf16.h>

#define B 128
#define N 2048
#define E 16384
#define F 32
#define H 64
#define OUTD 16
#define CAP 16

__device__ __forceinline__ float b2f(unsigned short u) {
    return __uint_as_float(((unsigned int)u) << 16);
}
__device__ __forceinline__ unsigned short f2b(float f) {
    unsigned int x = __float_as_uint(f);
    unsigned int r = (x + 0x7FFFu + ((x >> 16) & 1u)) >> 16;  // RNE, finite
    return (unsigned short)r;
}

struct PrepArgs {
    const void* src[9];
    float* dst[9];
};

// ---------------------------------------------------------------------------
// K0 (merged prep + graph build).
// Blocks 0..8: dtype probe (bf16 vs f32) + convert weights 1..8 to f32;
//   block 0 only writes flags[0] / flags[10].
// Blocks 9..9+B-1: per-batch graph build, cnt in LDS, two passes over the
//   batch's edge slice. Emits n_arr, dis, degc (min(deg,CAP)), ssrc (ushort
//   capacity-CSR), overflow list (unconditionally correct), zeroes pooled.
// ---------------------------------------------------------------------------
__global__ __launch_bounds__(256) void k_prep_build(
    PrepArgs pa, const int* __restrict__ eidx, const void* __restrict__ mask,
    int* flags, int* __restrict__ n_arr, float* __restrict__ dis,
    unsigned char* __restrict__ degc, unsigned short* __restrict__ ssrc,
    int2* __restrict__ ovf, int* __restrict__ ovf_cnt,
    float* __restrict__ pooled) {
    const int bid = blockIdx.x;
    const int t = threadIdx.x;
    if (bid < 9) {
        int sz;
        switch (bid) {
            case 0: sz = B * N * F; break;
            case 1: sz = F * H; break;
            case 2: sz = H; break;
            case 3: sz = H * H; break;
            case 4: sz = H; break;
            case 5: sz = H * H; break;
            case 6: sz = H; break;
            case 7: sz = H * OUTD; break;
            default: sz = OUTD; break;
        }
        const int K = sz < 1024 ? sz : 1024;
        const unsigned short* p = (const unsigned short*)pa.src[bid];
        float s = 0.f;
        for (int i = t; i < K; i += 256) s += fminf(fabsf(b2f(p[i])), 1e6f);
        __shared__ float red[256];
        __shared__ int isbf;
        red[t] = s;
        __syncthreads();
        for (int st = 128; st > 0; st >>= 1) {
            if (t < st) red[t] += red[t + st];
            __syncthreads();
        }
        if (t == 0) {
            int f = (red[0] < 100.0f * (float)K) ? 1 : 0;
            isbf = f;
            if (bid == 0) { flags[0] = f; flags[10] = 1; }
        }
        __syncthreads();
        if (bid == 0) return;
        const int fl = isbf;
        float* dst = pa.dst[bid];
        for (int i = t; i < sz; i += 256)
            dst[i] = fl ? b2f(((const unsigned short*)pa.src[bid])[i])
                        : ((const float*)pa.src[bid])[i];
        return;
    }
    // ---- build part ----
    __shared__ int s_cnt[N];
    __shared__ int s_red[256];
    __shared__ int s_n;
    __shared__ int s_ovf;
    const int b = bid - 9;
    const int bN = b * N;
    const unsigned char* mb = (const unsigned char*)mask;
    int mode;
    if (mb[0] == 0x80 && mb[1] == 0x3F) mode = 2;        // bf16
    else if (mb[0] != 0 && mb[1] != 0) mode = 0;         // bytes
    else if (mb[0] != 0) mode = (mb[4] != 0) ? 1 : 4;    // int32 : int64
    else mode = 3;                                       // f32
    int cnt = 0;
    if (mode == 0) {
        const unsigned char* r = mb + (size_t)b * N;
        for (int i = t; i < N; i += 256) cnt += (r[i] != 0);
    } else if (mode == 1 || mode == 3) {
        const unsigned int* r = (const unsigned int*)mask + (size_t)b * N;
        for (int i = t; i < N; i += 256) cnt += (r[i] != 0);
    } else if (mode == 2) {
        const unsigned short* r = (const unsigned short*)mask + (size_t)b * N;
        for (int i = t; i < N; i += 256) cnt += (r[i] != 0);
    } else {
        const unsigned long long* r = (const unsigned long long*)mask + (size_t)b * N;
        for (int i = t; i < N; i += 256) cnt += (r[i] != 0ULL);
    }
    s_red[t] = cnt;
    for (int i = t; i < N; i += 256) s_cnt[i] = 0;
    if (t == 0) s_ovf = 0;
    __syncthreads();
    if (t < 128) s_red[t] += s_red[t + 128];
    __syncthreads();
    if (t < 64) s_red[t] += s_red[t + 64];
    __syncthreads();
    if (t == 0) {
        int acc = 0;
        for (int i = 0; i < 64; i++) acc += s_red[i];
        s_n = acc > N ? N : acc;
    }
    __syncthreads();
    const int n = s_n;
    const int* es = eidx + (size_t)b * 2 * E;
    const int* ed = es + E;
    for (int i = t; i < E; i += 256) {
        int src = es[i], dst = ed[i];
        if ((unsigned)src < (unsigned)n && (unsigned)dst < (unsigned)n)
            atomicAdd(&s_cnt[dst], 1);
    }
    __syncthreads();
    for (int v = t; v < N; v += 256) {
        int c = s_cnt[v];
        dis[bN + v] = (v < n) ? rsqrtf((float)(c + 1)) : 0.0f;
        degc[bN + v] = (unsigned char)(c < CAP ? c : CAP);
        s_cnt[v] = 0;
    }
    __syncthreads();
    for (int i = t; i < E; i += 256) {
        int src = es[i], dst = ed[i];
        if ((unsigned)src < (unsigned)n && (unsigned)dst < (unsigned)n) {
            int pos = atomicAdd(&s_cnt[dst], 1);
            if (pos < CAP)
                ssrc[((size_t)(bN + dst)) * CAP + pos] = (unsigned short)src;
            else {
                int oi = atomicAdd(&s_ovf, 1);
                if (oi < E) ovf[(size_t)b * E + oi] = make_int2(dst, src);
            }
        }
    }
    if (t == 0) { n_arr[b] = n; ovf_cnt[b] = s_ovf; }
    if (t < H) pooled[b * H + t] = 0.0f;
}

// ---------------------------------------------------------------------------
// K1: GEMM + dis-premultiply epilogue: out[row] = dis[row] * (in[row] @ W),
// stored bf16. 64 rows/block (single batch: N%64==0), 4 rows x 4 cols/thread.
// ---------------------------------------------------------------------------
template <int FIN>
__global__ __launch_bounds__(256) void k_gemm(const void* __restrict__ in,
                                              const int* __restrict__ bf16flag,
                                              const float* __restrict__ W,
                                              const float* __restrict__ dis,
                                              unsigned short* __restrict__ out) {
    __shared__ float As[64][FIN + 4];
    __shared__ float Ws[FIN * H];
    __shared__ float s_dv[64];
    const int tid = threadIdx.x;
    const size_t row0 = (size_t)blockIdx.x * 64;
    for (int i = tid; i < FIN * H; i += 256) Ws[i] = W[i];
    if (tid < 64) s_dv[tid] = dis[row0 + tid];
    const int total = 64 * FIN;
    if (*bf16flag) {
        const unsigned short* ip = (const unsigned short*)in + row0 * FIN;
        for (int i = tid * 4; i < total; i += 1024) {
            ushort4 u = *(const ushort4*)(ip + i);
            int r = i / FIN, f = i & (FIN - 1);
            As[r][f] = b2f(u.x); As[r][f + 1] = b2f(u.y);
            As[r][f + 2] = b2f(u.z); As[r][f + 3] = b2f(u.w);
        }
    } else {
        const float* ip = (const float*)in + row0 * FIN;
        for (int i = tid * 4; i < total; i += 1024) {
            float4 u = *(const float4*)(ip + i);
            int r = i / FIN, f = i & (FIN - 1);
            As[r][f] = u.x; As[r][f + 1] = u.y;
            As[r][f + 2] = u.z; As[r][f + 3] = u.w;
        }
    }
    __syncthreads();
    const int r0 = (tid >> 4) * 4;
    const int cg = (tid & 15) * 4;
    float acc[4][4] = {};
    for (int f = 0; f < FIN; f++) {
        float4 w = *(const float4*)&Ws[f * H + cg];
#pragma unroll
        for (int rr = 0; rr < 4; rr++) {
            float a = As[r0 + rr][f];
            acc[rr][0] += a * w.x; acc[rr][1] += a * w.y;
            acc[rr][2] += a * w.z; acc[rr][3] += a * w.w;
        }
    }
#pragma unroll
    for (int rr = 0; rr < 4; rr++) {
        const float dv = s_dv[r0 + rr];
        ushort4 o;
        o.x = f2b(acc[rr][0] * dv); o.y = f2b(acc[rr][1] * dv);
        o.z = f2b(acc[rr][2] * dv); o.w = f2b(acc[rr][3] * dv);
        *(ushort4*)&out[(row0 + r0 + rr) * H + cg] = o;
    }
}

// ---------------------------------------------------------------------------
// K2: aggregation v5. hW is dis-premultiplied, so per edge: LDS idx read +
// masked global row load + add (no dis lookup, no multiply). Unroll-4 with
// predicated adds -> 4 outstanding loads/wave. Block = 64 nodes, LDS ~3.4 KB.
// out = relu(dv*(hW'[v] + sum_s hW'[s]) + bias); MODE 1 accumulates pool.
// ---------------------------------------------------------------------------
template <int MODE>
__global__ __launch_bounds__(256) void k_agg(
    const unsigned short* __restrict__ hW, const float* __restrict__ dis,
    const unsigned char* __restrict__ degc, const unsigned short* __restrict__ ssrc,
    const int2* __restrict__ ovf, const int* __restrict__ ovf_cnt,
    const float* __restrict__ bias, unsigned short* __restrict__ outb,
    float* __restrict__ pooled) {
    __shared__ unsigned short s_e[64 * CAP];
    __shared__ unsigned char s_dg[64];
    __shared__ float s_dv[64];
    __shared__ float s_red[4][64];
    const int bid = blockIdx.x;  // B*32
    const int b = bid >> 5;
    const int v0 = (bid & 31) * 64;
    const int t = threadIdx.x;
    const int bN = b * N;
    if (t < 128)  // 128 int4 = 1024 ushort edge slots
        ((int4*)s_e)[t] = ((const int4*)(ssrc + (size_t)(bN + v0) * CAP))[t];
    if (t < 16)
        ((unsigned int*)s_dg)[t] = ((const unsigned int*)(degc + bN + v0))[t];
    if (t >= 64 && t < 128) s_dv[t - 64] = dis[bN + v0 + (t - 64)];
    __syncthreads();
    const int lane = t & 63;
    const int w = t >> 6;
    const float bi = bias[lane];
    const int oc = ovf_cnt[b];
    const unsigned short* hWb = hW + (size_t)bN * H;
    float psum = 0.0f;
    int v = v0 + w * 16;
    for (int k = 0; k < 16; k++, v++) {
        const int nn = w * 16 + k;
        const int dg = s_dg[nn];
        const float dv = s_dv[nn];
        float acc0 = b2f(hWb[(v << 6) + lane]);  // self term (premultiplied)
        float acc1 = 0.0f;
        const unsigned short* ep = &s_e[nn * CAP];
        for (int i = 0; i < dg; i += 4) {
            int i0 = ep[i] & (N - 1);
            int i1 = ep[i + 1] & (N - 1);
            int i2 = ep[i + 2] & (N - 1);
            int i3 = ep[i + 3] & (N - 1);
            float h0 = b2f(hWb[(i0 << 6) + lane]);
            float h1 = b2f(hWb[(i1 << 6) + lane]);
            float h2 = b2f(hWb[(i2 << 6) + lane]);
            float h3 = b2f(hWb[(i3 << 6) + lane]);
            acc0 += h0;  // i < dg by loop condition
            acc1 += (i + 1 < dg) ? h1 : 0.0f;
            acc0 += (i + 2 < dg) ? h2 : 0.0f;
            acc1 += (i + 3 < dg) ? h3 : 0.0f;
        }
        if (oc > 0) {  // deg > CAP spill path; ~never taken
            const int2* ob = ovf + (size_t)b * E;
            for (int j = 0; j < oc; j++) {
                int2 o = ob[j];
                if (o.x == v) acc0 += b2f(hWb[(o.y << 6) + lane]);
            }
        }
        float res = (dv > 0.0f) ? fmaxf(fmaf(dv, acc0 + acc1, bi), 0.0f) : 0.0f;
        if (MODE == 0) outb[(size_t)((bN + v) << 6) + lane] = f2b(res);
        else psum += res;
    }
    if (MODE == 1) {
        s_red[w][lane] = psum;
        __syncthreads();
        if (w == 0)
            atomicAdd(&pooled[b * H + lane],
                      s_red[0][lane] + s_red[1][lane] + s_red[2][lane] + s_red[3][lane]);
    }
}

// ---------------------------------------------------------------------------
// K3: MLP head, one wave per batch.
// ---------------------------------------------------------------------------
__global__ __launch_bounds__(64) void k_mlp(
    const float* __restrict__ pooled, const int* __restrict__ n_arr,
    const float* __restrict__ aW1, const float* __restrict__ ab1,
    const float* __restrict__ aW2, const float* __restrict__ ab2,
    const int* __restrict__ flags, void* __restrict__ out) {
    const int b = blockIdx.x;
    const int t = threadIdx.x;
    __shared__ float p[64];
    __shared__ float hid[64];
    int n = n_arr[b];
    if (n < 1) n = 1;
    p[t] = pooled[b * H + t] / (float)n;
    __syncthreads();
    float acc = ab1[t];
    for (int j = 0; j < 64; j++) acc += p[j] * aW1[j * 64 + t];
    hid[t] = fmaxf(acc, 0.0f);
    __syncthreads();
    if (t < 16) {
        float a2 = ab2[t];
        for (int j = 0; j < 64; j++) a2 += hid[j] * aW2[j * 16 + t];
        if (flags[0]) ((unsigned short*)out)[b * OUTD + t] = f2b(a2);
        else          ((float*)out)[b * OUTD + t] = a2;
    }
}

// ---------------------------------------------------------------------------
extern "C" void kernel_launch(void* const* d_in, const int* in_sizes, int n_in,
                              void* d_out, int out_size, void* d_ws, size_t ws_size,
                              hipStream_t stream) {
    const void* x    = d_in[0];
    const int*  eidx = (const int*)d_in[1];
    const void* mask = d_in[2];

    char* ws = (char*)d_ws;
    size_t off = 0;
    auto alloc = [&](size_t bytes) -> void* {
        void* p = ws + off;
        off += (bytes + 255) & ~(size_t)255;
        return p;
    };
    int*   flags   = (int*)alloc(16 * sizeof(int));
    float* W1f     = (float*)alloc(F * H * sizeof(float));
    float* b1f     = (float*)alloc(H * sizeof(float));
    float* W2f     = (float*)alloc(H * H * sizeof(float));
    float* b2f_    = (float*)alloc(H * sizeof(float));
    float* aW1f    = (float*)alloc(H * H * sizeof(float));
    float* ab1f    = (float*)alloc(H * sizeof(float));
    float* aW2f    = (float*)alloc(H * OUTD * sizeof(float));
    float* ab2f    = (float*)alloc(OUTD * sizeof(float));
    int*   n_arr   = (int*)alloc(B * sizeof(int));
    float* dis     = (float*)alloc((size_t)B * N * sizeof(float));
    unsigned char*  degc = (unsigned char*)alloc((size_t)B * N);
    unsigned short* ssrc = (unsigned short*)alloc((size_t)B * N * CAP * 2);
    int2*  ovf     = (int2*)alloc((size_t)B * E * sizeof(int2));
    int*   ovf_cnt = (int*)alloc(B * sizeof(int));
    float* pooled  = (float*)alloc((size_t)B * H * sizeof(float));
    unsigned short* bufA = (unsigned short*)alloc((size_t)B * N * H * 2);
    unsigned short* bufB = (unsigned short*)alloc((size_t)B * N * H * 2);

    PrepArgs pa;
    pa.src[0] = x;        pa.dst[0] = pooled;  // dst[0] unused
    pa.src[1] = d_in[3];  pa.dst[1] = W1f;
    pa.src[2] = d_in[4];  pa.dst[2] = b1f;
    pa.src[3] = d_in[5];  pa.dst[3] = W2f;
    pa.src[4] = d_in[6];  pa.dst[4] = b2f_;
    pa.src[5] = d_in[7];  pa.dst[5] = aW1f;
    pa.src[6] = d_in[8];  pa.dst[6] = ab1f;
    pa.src[7] = d_in[9];  pa.dst[7] = aW2f;
    pa.src[8] = d_in[10]; pa.dst[8] = ab2f;

    k_prep_build<<<9 + B, 256, 0, stream>>>(pa, eidx, mask, flags, n_arr, dis,
                                            degc, ssrc, ovf, ovf_cnt, pooled);
    // Layer 1: hW1' = dis * (x @ W1); h1 = agg(hW1') stored bf16
    k_gemm<F><<<(B * N) / 64, 256, 0, stream>>>(x, flags + 0, W1f, dis, bufA);
    k_agg<0><<<B * 32, 256, 0, stream>>>(bufA, dis, degc, ssrc, ovf, ovf_cnt,
                                         b1f, bufB, pooled);
    // Layer 2: hW2' = dis * (h1 @ W2); agg fused with pooling
    k_gemm<H><<<(B * N) / 64, 256, 0, stream>>>(bufB, flags + 10, W2f, dis, bufA);
    k_agg<1><<<B * 32, 256, 0, stream>>>(bufA, dis, degc, ssrc, ovf, ovf_cnt,
                                         b2f_, nullptr, pooled);
    // Head
    k_mlp<<<B, 64, 0, stream>>>(pooled, n_arr, aW1f, ab1f, aW2f, ab2f, flags, d_out);
}

// Round 7
// 256.699 us; speedup vs baseline: 2.7972x; 1.2300x over previous
//
#include <hip/hip_runtime.h>
#include <hip/hip_bf16.h>

#define B 128
#define N 2048
#define E 16384
#define F 32
#define H 64
#define OUTD 16
#define CAP 16

__device__ __forceinline__ float b2f(unsigned short u) {
    return __uint_as_float(((unsigned int)u) << 16);
}
__device__ __forceinline__ unsigned short f2b(float f) {
    unsigned int x = __float_as_uint(f);
    unsigned int r = (x + 0x7FFFu + ((x >> 16) & 1u)) >> 16;  // RNE, finite
    return (unsigned short)r;
}

struct PrepArgs {
    const void* src[9];
    float* dst[9];
};

// ---------------------------------------------------------------------------
// K0: prep (9 blocks). Dtype probe + weight conversion to f32.
// ---------------------------------------------------------------------------
__global__ __launch_bounds__(256) void k_prep(PrepArgs pa, int* flags) {
    const int bid = blockIdx.x;
    const int t = threadIdx.x;
    int sz;
    switch (bid) {
        case 0: sz = B * N * F; break;
        case 1: sz = F * H; break;
        case 2: sz = H; break;
        case 3: sz = H * H; break;
        case 4: sz = H; break;
        case 5: sz = H * H; break;
        case 6: sz = H; break;
        case 7: sz = H * OUTD; break;
        default: sz = OUTD; break;
    }
    const int K = sz < 1024 ? sz : 1024;
    const unsigned short* p = (const unsigned short*)pa.src[bid];
    float s = 0.f;
    for (int i = t; i < K; i += 256) s += fminf(fabsf(b2f(p[i])), 1e6f);
    __shared__ float red[256];
    __shared__ int isbf;
    red[t] = s;
    __syncthreads();
    for (int st = 128; st > 0; st >>= 1) {
        if (t < st) red[t] += red[t + st];
        __syncthreads();
    }
    if (t == 0) {
        int f = (red[0] < 100.0f * (float)K) ? 1 : 0;
        isbf = f;
        if (bid == 0) { flags[0] = f; flags[10] = 1; }
    }
    __syncthreads();
    if (bid == 0) return;
    const int fl = isbf;
    float* dst = pa.dst[bid];
    for (int i = t; i < sz; i += 256)
        dst[i] = fl ? b2f(((const unsigned short*)pa.src[bid])[i])
                    : ((const float*)pa.src[bid])[i];
}

// ---------------------------------------------------------------------------
// K1: graph build. One block of 1024 threads per batch (16 waves). int4-
// vectorized edge loads. cnt in LDS; two passes. Emits n_arr, dis, degc,
// ssrc (ushort capacity-CSR), overflow list; zeroes pooled.
// ---------------------------------------------------------------------------
__global__ __launch_bounds__(1024) void k_build(
    const int* __restrict__ eidx, const void* __restrict__ mask,
    int* __restrict__ n_arr, float* __restrict__ dis,
    unsigned char* __restrict__ degc, unsigned short* __restrict__ ssrc,
    int2* __restrict__ ovf, int* __restrict__ ovf_cnt,
    float* __restrict__ pooled) {
    __shared__ int s_cnt[N];
    __shared__ int s_w[16];
    __shared__ int s_n;
    __shared__ int s_ovf;
    const int b = blockIdx.x;
    const int t = threadIdx.x;
    const int bN = b * N;
    // mask mode detect (uniform) + count n
    const unsigned char* mb = (const unsigned char*)mask;
    int mode;
    if (mb[0] == 0x80 && mb[1] == 0x3F) mode = 2;        // bf16
    else if (mb[0] != 0 && mb[1] != 0) mode = 0;         // bytes
    else if (mb[0] != 0) mode = (mb[4] != 0) ? 1 : 4;    // int32 : int64
    else mode = 3;                                       // f32
    int cnt = 0;
    if (mode == 0) {
        const unsigned char* r = mb + (size_t)b * N;
        for (int i = t; i < N; i += 1024) cnt += (r[i] != 0);
    } else if (mode == 1 || mode == 3) {
        const unsigned int* r = (const unsigned int*)mask + (size_t)b * N;
        for (int i = t; i < N; i += 1024) cnt += (r[i] != 0);
    } else if (mode == 2) {
        const unsigned short* r = (const unsigned short*)mask + (size_t)b * N;
        for (int i = t; i < N; i += 1024) cnt += (r[i] != 0);
    } else {
        const unsigned long long* r = (const unsigned long long*)mask + (size_t)b * N;
        for (int i = t; i < N; i += 1024) cnt += (r[i] != 0ULL);
    }
    for (int o = 32; o > 0; o >>= 1) cnt += __shfl_down(cnt, o);
    if ((t & 63) == 0) s_w[t >> 6] = cnt;
    for (int i = t; i < N; i += 1024) s_cnt[i] = 0;
    if (t == 0) s_ovf = 0;
    __syncthreads();
    if (t == 0) {
        int a = 0;
        for (int i = 0; i < 16; i++) a += s_w[i];
        s_n = a > N ? N : a;
    }
    __syncthreads();
    const int n = s_n;
    const int4* es4 = (const int4*)(eidx + (size_t)b * 2 * E);
    const int4* ed4 = es4 + E / 4;
    // pass 1: count (4 edges per thread per iter)
    for (int i = t; i < E / 4; i += 1024) {
        int4 s4 = es4[i], d4 = ed4[i];
        if ((unsigned)s4.x < (unsigned)n && (unsigned)d4.x < (unsigned)n) atomicAdd(&s_cnt[d4.x], 1);
        if ((unsigned)s4.y < (unsigned)n && (unsigned)d4.y < (unsigned)n) atomicAdd(&s_cnt[d4.y], 1);
        if ((unsigned)s4.z < (unsigned)n && (unsigned)d4.z < (unsigned)n) atomicAdd(&s_cnt[d4.z], 1);
        if ((unsigned)s4.w < (unsigned)n && (unsigned)d4.w < (unsigned)n) atomicAdd(&s_cnt[d4.w], 1);
    }
    __syncthreads();
    // emit dis/degc, reset cursors
    for (int v = t; v < N; v += 1024) {
        int c = s_cnt[v];
        dis[bN + v] = (v < n) ? rsqrtf((float)(c + 1)) : 0.0f;
        degc[bN + v] = (unsigned char)(c < CAP ? c : CAP);
        s_cnt[v] = 0;
    }
    __syncthreads();
    // pass 2: fill (edge slice L2-hot)
    for (int i = t; i < E / 4; i += 1024) {
        int4 s4 = es4[i], d4 = ed4[i];
#define FILL1(SS, DD)                                                          \
        if ((unsigned)(SS) < (unsigned)n && (unsigned)(DD) < (unsigned)n) {    \
            int pos = atomicAdd(&s_cnt[DD], 1);                                \
            if (pos < CAP)                                                     \
                ssrc[((size_t)(bN + (DD))) * CAP + pos] = (unsigned short)(SS);\
            else {                                                             \
                int oi = atomicAdd(&s_ovf, 1);                                 \
                if (oi < E) ovf[(size_t)b * E + oi] = make_int2((DD), (SS));   \
            }                                                                  \
        }
        FILL1(s4.x, d4.x) FILL1(s4.y, d4.y) FILL1(s4.z, d4.z) FILL1(s4.w, d4.w)
#undef FILL1
    }
    if (t == 0) { n_arr[b] = n; ovf_cnt[b] = s_ovf; }
    if (t < H) pooled[b * H + t] = 0.0f;
}

// ---------------------------------------------------------------------------
// K2: GEMM1 + dis premultiply: out[row] = dis[row] * (in[row] @ W), bf16.
// ---------------------------------------------------------------------------
template <int FIN>
__global__ __launch_bounds__(256) void k_gemm(const void* __restrict__ in,
                                              const int* __restrict__ bf16flag,
                                              const float* __restrict__ W,
                                              const float* __restrict__ dis,
                                              unsigned short* __restrict__ out) {
    __shared__ float As[64][FIN + 4];
    __shared__ float Ws[FIN * H];
    __shared__ float s_dv[64];
    const int tid = threadIdx.x;
    const size_t row0 = (size_t)blockIdx.x * 64;
    for (int i = tid; i < FIN * H; i += 256) Ws[i] = W[i];
    if (tid < 64) s_dv[tid] = dis[row0 + tid];
    const int total = 64 * FIN;
    if (*bf16flag) {
        const unsigned short* ip = (const unsigned short*)in + row0 * FIN;
        for (int i = tid * 4; i < total; i += 1024) {
            ushort4 u = *(const ushort4*)(ip + i);
            int r = i / FIN, f = i & (FIN - 1);
            As[r][f] = b2f(u.x); As[r][f + 1] = b2f(u.y);
            As[r][f + 2] = b2f(u.z); As[r][f + 3] = b2f(u.w);
        }
    } else {
        const float* ip = (const float*)in + row0 * FIN;
        for (int i = tid * 4; i < total; i += 1024) {
            float4 u = *(const float4*)(ip + i);
            int r = i / FIN, f = i & (FIN - 1);
            As[r][f] = u.x; As[r][f + 1] = u.y;
            As[r][f + 2] = u.z; As[r][f + 3] = u.w;
        }
    }
    __syncthreads();
    const int r0 = (tid >> 4) * 4;
    const int cg = (tid & 15) * 4;
    float acc[4][4] = {};
    for (int f = 0; f < FIN; f++) {
        float4 w = *(const float4*)&Ws[f * H + cg];
#pragma unroll
        for (int rr = 0; rr < 4; rr++) {
            float a = As[r0 + rr][f];
            acc[rr][0] += a * w.x; acc[rr][1] += a * w.y;
            acc[rr][2] += a * w.z; acc[rr][3] += a * w.w;
        }
    }
#pragma unroll
    for (int rr = 0; rr < 4; rr++) {
        const float dv = s_dv[r0 + rr];
        ushort4 o;
        o.x = f2b(acc[rr][0] * dv); o.y = f2b(acc[rr][1] * dv);
        o.z = f2b(acc[rr][2] * dv); o.w = f2b(acc[rr][3] * dv);
        *(ushort4*)&out[(row0 + r0 + rr) * H + cg] = o;
    }
}

// ---------------------------------------------------------------------------
// K3: agg layer-1 FUSED with GEMM2. Computes h1 tile (64x64) into LDS
// (never hits HBM), then out2 = dis * (h1 @ W2), bf16.
// XCD swizzle: all 32 blocks of a batch share bid&7.
// ---------------------------------------------------------------------------
__global__ __launch_bounds__(256) void k_agg_gemm(
    const unsigned short* __restrict__ hW, const float* __restrict__ dis,
    const unsigned char* __restrict__ degc, const unsigned short* __restrict__ ssrc,
    const int2* __restrict__ ovf, const int* __restrict__ ovf_cnt,
    const float* __restrict__ bias, const float* __restrict__ W2,
    unsigned short* __restrict__ out2) {
    __shared__ unsigned short s_e[64 * CAP];
    __shared__ unsigned char s_dg[64];
    __shared__ float s_dv[64];
    __shared__ float s_h1[64][H + 1];
    __shared__ float Ws[H * H];
    const int bid = blockIdx.x;  // B*32, swizzled
    const int b = (bid & 7) + ((bid >> 8) << 3);
    const int v0 = ((bid >> 3) & 31) * 64;
    const int t = threadIdx.x;
    const int bN = b * N;
    if (t < 128)
        ((int4*)s_e)[t] = ((const int4*)(ssrc + (size_t)(bN + v0) * CAP))[t];
    if (t < 16)
        ((unsigned int*)s_dg)[t] = ((const unsigned int*)(degc + bN + v0))[t];
    if (t >= 64 && t < 128) s_dv[t - 64] = dis[bN + v0 + (t - 64)];
    for (int i = t; i < H * H / 4; i += 256)
        ((float4*)Ws)[i] = ((const float4*)W2)[i];
    __syncthreads();
    const int lane = t & 63;
    const int w = t >> 6;
    const float bi = bias[lane];
    const int oc = ovf_cnt[b];
    const unsigned short* hWb = hW + (size_t)bN * H;
    int v = v0 + w * 16;
    for (int k = 0; k < 16; k++, v++) {
        const int nn = w * 16 + k;
        const int dg = s_dg[nn];
        const float dv = s_dv[nn];
        float res = 0.0f;
        if (dv > 0.0f) {
            float acc = b2f(hWb[(v << 6) + lane]);  // self (premultiplied)
            const unsigned short* ep = &s_e[nn * CAP];
            if (dg > 0) {
                float hh[8];
#pragma unroll
                for (int j = 0; j < 8; j++) {
                    int ij = ep[j] & (N - 1);
                    hh[j] = b2f(hWb[(ij << 6) + lane]);
                }
#pragma unroll
                for (int j = 0; j < 8; j++) acc += (j < dg) ? hh[j] : 0.0f;
                if (dg > 8) {
                    float h2[8];
#pragma unroll
                    for (int j = 0; j < 8; j++) {
                        int ij = ep[8 + j] & (N - 1);
                        h2[j] = b2f(hWb[(ij << 6) + lane]);
                    }
#pragma unroll
                    for (int j = 0; j < 8; j++) acc += (8 + j < dg) ? h2[j] : 0.0f;
                }
            }
            if (oc > 0) {  // deg > CAP spills; ~never taken
                const int2* ob = ovf + (size_t)b * E;
                for (int j = 0; j < oc; j++) {
                    int2 o = ob[j];
                    if (o.x == v) acc += b2f(hWb[(o.y << 6) + lane]);
                }
            }
            res = fmaxf(fmaf(dv, acc, bi), 0.0f);
        }
        s_h1[nn][lane] = res;
    }
    __syncthreads();
    // in-block GEMM: out2[r] = s_dv[r] * (s_h1[r] @ Ws)
    const int r0 = (t >> 4) * 4;
    const int cg = (t & 15) * 4;
    float acc[4][4] = {};
    for (int f = 0; f < H; f++) {
        float4 wv = *(const float4*)&Ws[f * H + cg];
#pragma unroll
        for (int rr = 0; rr < 4; rr++) {
            float a = s_h1[r0 + rr][f];
            acc[rr][0] += a * wv.x; acc[rr][1] += a * wv.y;
            acc[rr][2] += a * wv.z; acc[rr][3] += a * wv.w;
        }
    }
#pragma unroll
    for (int rr = 0; rr < 4; rr++) {
        const float dvr = s_dv[r0 + rr];
        ushort4 o;
        o.x = f2b(acc[rr][0] * dvr); o.y = f2b(acc[rr][1] * dvr);
        o.z = f2b(acc[rr][2] * dvr); o.w = f2b(acc[rr][3] * dvr);
        *(ushort4*)&out2[(size_t)(bN + v0 + r0 + rr) * H + cg] = o;
    }
}

// ---------------------------------------------------------------------------
// K4: agg layer-2 + pooling (h2 never materialized). Same swizzle/unroll.
// ---------------------------------------------------------------------------
__global__ __launch_bounds__(256) void k_agg_pool(
    const unsigned short* __restrict__ hW, const float* __restrict__ dis,
    const unsigned char* __restrict__ degc, const unsigned short* __restrict__ ssrc,
    const int2* __restrict__ ovf, const int* __restrict__ ovf_cnt,
    const float* __restrict__ bias, float* __restrict__ pooled) {
    __shared__ unsigned short s_e[64 * CAP];
    __shared__ unsigned char s_dg[64];
    __shared__ float s_dv[64];
    __shared__ float s_red[4][64];
    const int bid = blockIdx.x;
    const int b = (bid & 7) + ((bid >> 8) << 3);
    const int v0 = ((bid >> 3) & 31) * 64;
    const int t = threadIdx.x;
    const int bN = b * N;
    if (t < 128)
        ((int4*)s_e)[t] = ((const int4*)(ssrc + (size_t)(bN + v0) * CAP))[t];
    if (t < 16)
        ((unsigned int*)s_dg)[t] = ((const unsigned int*)(degc + bN + v0))[t];
    if (t >= 64 && t < 128) s_dv[t - 64] = dis[bN + v0 + (t - 64)];
    __syncthreads();
    const int lane = t & 63;
    const int w = t >> 6;
    const float bi = bias[lane];
    const int oc = ovf_cnt[b];
    const unsigned short* hWb = hW + (size_t)bN * H;
    float psum = 0.0f;
    int v = v0 + w * 16;
    for (int k = 0; k < 16; k++, v++) {
        const int nn = w * 16 + k;
        const int dg = s_dg[nn];
        const float dv = s_dv[nn];
        if (dv > 0.0f) {
            float acc = b2f(hWb[(v << 6) + lane]);
            const unsigned short* ep = &s_e[nn * CAP];
            if (dg > 0) {
                float hh[8];
#pragma unroll
                for (int j = 0; j < 8; j++) {
                    int ij = ep[j] & (N - 1);
                    hh[j] = b2f(hWb[(ij << 6) + lane]);
                }
#pragma unroll
                for (int j = 0; j < 8; j++) acc += (j < dg) ? hh[j] : 0.0f;
                if (dg > 8) {
                    float h2[8];
#pragma unroll
                    for (int j = 0; j < 8; j++) {
                        int ij = ep[8 + j] & (N - 1);
                        h2[j] = b2f(hWb[(ij << 6) + lane]);
                    }
#pragma unroll
                    for (int j = 0; j < 8; j++) acc += (8 + j < dg) ? h2[j] : 0.0f;
                }
            }
            if (oc > 0) {
                const int2* ob = ovf + (size_t)b * E;
                for (int j = 0; j < oc; j++) {
                    int2 o = ob[j];
                    if (o.x == v) acc += b2f(hWb[(o.y << 6) + lane]);
                }
            }
            psum += fmaxf(fmaf(dv, acc, bi), 0.0f);
        }
    }
    s_red[w][lane] = psum;
    __syncthreads();
    if (w == 0)
        atomicAdd(&pooled[b * H + lane],
                  s_red[0][lane] + s_red[1][lane] + s_red[2][lane] + s_red[3][lane]);
}

// ---------------------------------------------------------------------------
// K5: MLP head, one wave per batch.
// ---------------------------------------------------------------------------
__global__ __launch_bounds__(64) void k_mlp(
    const float* __restrict__ pooled, const int* __restrict__ n_arr,
    const float* __restrict__ aW1, const float* __restrict__ ab1,
    const float* __restrict__ aW2, const float* __restrict__ ab2,
    const int* __restrict__ flags, void* __restrict__ out) {
    const int b = blockIdx.x;
    const int t = threadIdx.x;
    __shared__ float p[64];
    __shared__ float hid[64];
    int n = n_arr[b];
    if (n < 1) n = 1;
    p[t] = pooled[b * H + t] / (float)n;
    __syncthreads();
    float acc = ab1[t];
    for (int j = 0; j < 64; j++) acc += p[j] * aW1[j * 64 + t];
    hid[t] = fmaxf(acc, 0.0f);
    __syncthreads();
    if (t < 16) {
        float a2 = ab2[t];
        for (int j = 0; j < 64; j++) a2 += hid[j] * aW2[j * 16 + t];
        if (flags[0]) ((unsigned short*)out)[b * OUTD + t] = f2b(a2);
        else          ((float*)out)[b * OUTD + t] = a2;
    }
}

// ---------------------------------------------------------------------------
extern "C" void kernel_launch(void* const* d_in, const int* in_sizes, int n_in,
                              void* d_out, int out_size, void* d_ws, size_t ws_size,
                              hipStream_t stream) {
    const void* x    = d_in[0];
    const int*  eidx = (const int*)d_in[1];
    const void* mask = d_in[2];

    char* ws = (char*)d_ws;
    size_t off = 0;
    auto alloc = [&](size_t bytes) -> void* {
        void* p = ws + off;
        off += (bytes + 255) & ~(size_t)255;
        return p;
    };
    int*   flags   = (int*)alloc(16 * sizeof(int));
    float* W1f     = (float*)alloc(F * H * sizeof(float));
    float* b1f     = (float*)alloc(H * sizeof(float));
    float* W2f     = (float*)alloc(H * H * sizeof(float));
    float* b2f_    = (float*)alloc(H * sizeof(float));
    float* aW1f    = (float*)alloc(H * H * sizeof(float));
    float* ab1f    = (float*)alloc(H * sizeof(float));
    float* aW2f    = (float*)alloc(H * OUTD * sizeof(float));
    float* ab2f    = (float*)alloc(OUTD * sizeof(float));
    int*   n_arr   = (int*)alloc(B * sizeof(int));
    float* dis     = (float*)alloc((size_t)B * N * sizeof(float));
    unsigned char*  degc = (unsigned char*)alloc((size_t)B * N);
    unsigned short* ssrc = (unsigned short*)alloc((size_t)B * N * CAP * 2);
    int2*  ovf     = (int2*)alloc((size_t)B * E * sizeof(int2));
    int*   ovf_cnt = (int*)alloc(B * sizeof(int));
    float* pooled  = (float*)alloc((size_t)B * H * sizeof(float));
    unsigned short* buf1 = (unsigned short*)alloc((size_t)B * N * H * 2);  // hW1'
    unsigned short* buf2 = (unsigned short*)alloc((size_t)B * N * H * 2);  // hW2'

    PrepArgs pa;
    pa.src[0] = x;        pa.dst[0] = pooled;  // dst[0] unused
    pa.src[1] = d_in[3];  pa.dst[1] = W1f;
    pa.src[2] = d_in[4];  pa.dst[2] = b1f;
    pa.src[3] = d_in[5];  pa.dst[3] = W2f;
    pa.src[4] = d_in[6];  pa.dst[4] = b2f_;
    pa.src[5] = d_in[7];  pa.dst[5] = aW1f;
    pa.src[6] = d_in[8];  pa.dst[6] = ab1f;
    pa.src[7] = d_in[9];  pa.dst[7] = aW2f;
    pa.src[8] = d_in[10]; pa.dst[8] = ab2f;

    k_prep<<<9, 256, 0, stream>>>(pa, flags);
    k_build<<<B, 1024, 0, stream>>>(eidx, mask, n_arr, dis, degc, ssrc, ovf,
                                    ovf_cnt, pooled);
    // hW1' = dis * (x @ W1)
    k_gemm<F><<<(B * N) / 64, 256, 0, stream>>>(x, flags + 0, W1f, dis, buf1);
    // h1 tile in LDS -> hW2' = dis * (h1 @ W2)  (h1 never hits HBM)
    k_agg_gemm<<<B * 32, 256, 0, stream>>>(buf1, dis, degc, ssrc, ovf, ovf_cnt,
                                           b1f, W2f, buf2);
    // h2 = agg(hW2') fused with pooling (h2 never stored)
    k_agg_pool<<<B * 32, 256, 0, stream>>>(buf2, dis, degc, ssrc, ovf, ovf_cnt,
                                           b2f_, pooled);
    // Head
    k_mlp<<<B, 64, 0, stream>>>(pooled, n_arr, aW1f, ab1f, aW2f, ab2f, flags, d_out);
}